// Round 7
// baseline (238.529 us; speedup 1.0000x reference)
//
#include <hip/hip_runtime.h>
#include <math.h>

typedef _Float16 f16;
typedef __fp16 h16x2 __attribute__((ext_vector_type(2)));
typedef _Float16 f16x4 __attribute__((ext_vector_type(4)));
typedef _Float16 f16x8 __attribute__((ext_vector_type(8)));
typedef float f32x4 __attribute__((ext_vector_type(4)));
typedef float f32x16 __attribute__((ext_vector_type(16)));
typedef unsigned int u32;

#define D_MODEL 1024
#define NHEADS 16
#define DHEAD 64
#define LQ 2048
#define LKK 2048
#define BB 2
#define LOG2E 1.4426950408889634f

static __device__ __forceinline__ void gload16(const void* g, void* l) {
  __builtin_amdgcn_global_load_lds(
      (const __attribute__((address_space(1))) u32*)g,
      (__attribute__((address_space(3))) u32*)l, 16, 0, 0);
}
static __device__ __forceinline__ float ex2(float x) {
  float r;
  asm volatile("v_exp_f32 %0, %1\n\ts_nop 0" : "=v"(r) : "v"(x));
  return r;
}
static __device__ __forceinline__ u32 pkr(float a, float b) {
  union { h16x2 h; u32 u; } c;
  c.h = __builtin_amdgcn_cvt_pkrtz(a, b);
  return c.u;
}
static __device__ __forceinline__ float fmax3(float a, float b, float c) {
  return fmaxf(fmaxf(a, b), c);  // clang fuses to v_max3_f32
}
#define MFMA16(a, b, c) __builtin_amdgcn_mfma_f32_16x16x32_f16(a, b, c, 0, 0, 0)
#define MFMA32(a, b, c) __builtin_amdgcn_mfma_f32_32x32x16_f16(a, b, c, 0, 0, 0)

// ---------------- W convert + prep (mask detect/convert, bias table) ----------------
__global__ void k_cvtw_prep(const float* Wq, const float* Wk, const float* Wv, const float* Wo,
                            f16* W16, const void* msk, const float* __restrict__ rel,
                            float* __restrict__ biasT, unsigned char* __restrict__ m8) {
  const int blk = blockIdx.x;
  const int t = threadIdx.x;
  if (blk < 4096) {  // W fp32->fp16: 4 x 1M elems = 1M float4
    int i = blk * 256 + t;
    int which = i >> 18, off = i & 262143;
    const float* s = which == 0 ? Wq : (which == 1 ? Wk : (which == 2 ? Wv : Wo));
    float4 x = ((const float4*)s)[off];
    f16x4 o; o[0] = (f16)x.x; o[1] = (f16)x.y; o[2] = (f16)x.z; o[3] = (f16)x.w;
    ((f16x4*)(W16 + (size_t)which * 1048576))[off] = o;
    return;
  }
  if (blk == 4096) {  // mask dtype detect + convert to u8
    __shared__ int o1s, o2s;
    if (t == 0) { o1s = 0; o2s = 0; }
    __syncthreads();
    const unsigned char* raw = (const unsigned char*)msk;
    int o1 = 0, o2 = 0;
    for (int i = t; i < BB * LKK; i += 256) {
      unsigned char vv = raw[i];
      if ((i & 3) && vv) o1 = 1;
      if (((i & 3) == 2) && vv == 0x80u) o2 = 1;
    }
    if (o1) atomicOr(&o1s, 1);
    if (o2) atomicOr(&o2s, 1);
    __syncthreads();
    const int f = o1s ? (o2s ? 2 : 1) : 0;  // 0=int32, 1=bool, 2=f32
    for (int i = t; i < BB * LKK; i += 256) {
      unsigned char v;
      if (f == 0)      v = (((const int*)msk)[i] != 0);
      else if (f == 1) v = (((const unsigned char*)msk)[i] != 0);
      else             v = (((const float*)msk)[i] != 0.0f);
      m8[i] = v;
    }
    return;
  }
  // blk == 4097: bias table, pre-scaled by log2e
  for (int n = t; n < 2048; n += 256) {
    int bucket;
    if (n < 16) bucket = n;
    else {
      float tt = logf((float)n / 16.0f + 1e-9f);  // exact jax op order
      tt = tt / 2.0794415416798357f;
      tt = tt * 16.0f;
      bucket = 16 + (int)tt;
      if (bucket > 31) bucket = 31;
    }
    for (int h = 0; h < NHEADS; ++h)
      biasT[h * 2048 + n] = rel[bucket * NHEADS + h] * LOG2E;
  }
}

// ---------------- GEMM core: C = A[4096,1024] * B[1024,1024]^T, tile 128 x BN ----------------
// Double-buffered LDS, ONE barrier per K-step; AF32: A fp32 reg-staged (loads issued at
// phase start, latency covered by the MFMA phase), fused RTE cvt.
// EPI 0: f16 scatter [B,H,L,64].  EPI 1: fp32 row-major.  EPI 2: f16 V^T [B,H,64,L].
template <int EPI, int BN, bool AF32>
static __device__ __forceinline__ void gemm_core(const void* __restrict__ Av,
                                                 const f16* __restrict__ Bm,
                                                 void* __restrict__ C) {
  constexpr int JN = BN / 32;  // col frags per wave
  __shared__ __align__(16) f16 sA[2][128 * 32];
  __shared__ __align__(16) f16 sB[2][BN * 32];
  const int t = threadIdx.x;
  const int w = t >> 6, lane = t & 63;
  const int lg = lane >> 4, lc = lane & 15;
  const int wr = w >> 1, wc = w & 1;
  const long row0 = (long)blockIdx.x * 128;
  const long col0 = (long)blockIdx.y * BN;
  f32x4 acc[4][JN] = {};

  const int rA0 = t >> 2, kA0 = t & 3;           // chunk t
  const int rA1 = (t + 256) >> 2, kA1 = t & 3;   // chunk t+256

  float4 a[4];  // reg stage for AF32 (2 chunks x 2 float4)

  auto LOADA = [&](int kk) {
    const float* s0 = (const float*)Av + (row0 + rA0) * 1024 + kk * 32 + kA0 * 8;
    const float* s1 = (const float*)Av + (row0 + rA1) * 1024 + kk * 32 + kA1 * 8;
    a[0] = *(const float4*)s0; a[1] = *(const float4*)(s0 + 4);
    a[2] = *(const float4*)s1; a[3] = *(const float4*)(s1 + 4);
  };
  auto WRITEA = [&](int buf) {
    f16x8 o0, o1;
    o0[0] = (f16)a[0].x; o0[1] = (f16)a[0].y; o0[2] = (f16)a[0].z; o0[3] = (f16)a[0].w;
    o0[4] = (f16)a[1].x; o0[5] = (f16)a[1].y; o0[6] = (f16)a[1].z; o0[7] = (f16)a[1].w;
    o1[0] = (f16)a[2].x; o1[1] = (f16)a[2].y; o1[2] = (f16)a[2].z; o1[3] = (f16)a[2].w;
    o1[4] = (f16)a[3].x; o1[5] = (f16)a[3].y; o1[6] = (f16)a[3].z; o1[7] = (f16)a[3].w;
    *(f16x8*)((char*)&sA[buf][0] + t * 16) = o0;
    *(f16x8*)((char*)&sA[buf][0] + (t + 256) * 16) = o1;
  };
  auto STAGEA16 = [&](int kk, int buf) {
    gload16((const f16*)Av + (row0 + rA0) * 1024 + kk * 32 + kA0 * 8,
            (char*)&sA[buf][0] + t * 16);
    gload16((const f16*)Av + (row0 + rA1) * 1024 + kk * 32 + kA1 * 8,
            (char*)&sA[buf][0] + (t + 256) * 16);
  };
  auto STAGEB = [&](int kk, int buf) {
#pragma unroll
    for (int it = 0; it < BN / 64; ++it) {
      int ch = t + it * 256;
      int r = ch >> 2, kq = ch & 3;
      gload16(Bm + (col0 + r) * 1024 + kk * 32 + kq * 8, (char*)&sB[buf][0] + ch * 16);
    }
  };
  auto COMPUTE = [&](int buf) {
    f16x8 af[4], bf[JN];
#pragma unroll
    for (int i = 0; i < 4; ++i)
      af[i] = *(const f16x8*)&sA[buf][(wr * 64 + i * 16 + lc) * 32 + lg * 8];
#pragma unroll
    for (int j = 0; j < JN; ++j)
      bf[j] = *(const f16x8*)&sB[buf][(wc * (16 * JN) + j * 16 + lc) * 32 + lg * 8];
#pragma unroll
    for (int i = 0; i < 4; ++i)
#pragma unroll
      for (int j = 0; j < JN; ++j)
        acc[i][j] = MFMA16(af[i], bf[j], acc[i][j]);
  };

  // prologue: stage K-step 0 into buf 0
  if constexpr (AF32) { LOADA(0); } else { STAGEA16(0, 0); }
  STAGEB(0, 0);
  if constexpr (AF32) WRITEA(0);
  __syncthreads();

  for (int kk = 0; kk < 32; ++kk) {
    const int cur = kk & 1;
    if (kk < 31) {  // issue next-step loads BEFORE compute (latency hides under MFMA)
      if constexpr (AF32) { LOADA(kk + 1); } else { STAGEA16(kk + 1, cur ^ 1); }
      STAGEB(kk + 1, cur ^ 1);
    }
    COMPUTE(cur);
    if (kk < 31) { if constexpr (AF32) WRITEA(cur ^ 1); }
    __syncthreads();
  }

#pragma unroll
  for (int i = 0; i < 4; ++i)
#pragma unroll
    for (int j = 0; j < JN; ++j) {
      const long rowb = row0 + wr * 64 + i * 16 + lg * 4;
      const long col = col0 + wc * (16 * JN) + j * 16 + lc;
      if (EPI == 2) {  // V^T: [b,h,d,l] with f16x4 over l
        long b = rowb >> 11, l0 = rowb & 2047;
        long h = col >> 6, d = col & 63;
        f16x4 ov;
#pragma unroll
        for (int r = 0; r < 4; ++r) ov[r] = (f16)acc[i][j][r];
        *(f16x4*)((f16*)C + (((b * NHEADS + h) * DHEAD + d) * (long)LKK + l0)) = ov;
      } else {
#pragma unroll
        for (int r = 0; r < 4; ++r) {
          long row = rowb + r;
          float v = acc[i][j][r];
          if (EPI == 0) {
            long b = row >> 11, l = row & 2047;
            long h = col >> 6, d = col & 63;
            ((f16*)C)[(((b * NHEADS + h) * LQ) + l) * DHEAD + d] = (f16)v;
          } else {
            ((float*)C)[row * 1024 + col] = v;
          }
        }
      }
    }
}

__global__ void __launch_bounds__(256, 4)
k_gemm_qkv(const float* __restrict__ q, const float* __restrict__ k, const float* __restrict__ v,
           const f16* __restrict__ W16, f16* __restrict__ QHp, f16* __restrict__ KHp,
           f16* __restrict__ VTp) {
  const int z = blockIdx.z;
  if (z == 2) {
    gemm_core<2, 128, true>(v, W16 + 2 * 1048576, VTp);
  } else {
    const float* A = z == 0 ? q : k;
    f16* C = z == 0 ? QHp : KHp;
    gemm_core<0, 128, true>(A, W16 + (size_t)z * 1048576, C);
  }
}

__global__ void __launch_bounds__(256, 4)
k_gemm_o(const f16* __restrict__ A, const f16* __restrict__ Bm, float* __restrict__ C) {
  gemm_core<1, 64, false>(A, Bm, C);
}

// ---------------- flash attention: barrier-free, direct K/V operand loads from L2 ----------------
// 4 warps/block, 32 q-rows/warp. SPLIT=1: grid 512. SPLIT=2: grid 1024, each block does half
// the KV range, writes normalized partial O (f16) + (m,l); combine kernel merges.
// K frag = 16B contiguous in KH[k][d]; V^T frag = 16B contiguous in VT[d][l]. No K/V LDS.
template <int SPLIT>
__global__ void __launch_bounds__(256, 4)
k_attn(const f16* __restrict__ QH, const f16* __restrict__ KH, const f16* __restrict__ VT,
       const float* __restrict__ BIASg, const unsigned char* __restrict__ M8,
       f16* __restrict__ OUT, float* __restrict__ ML) {
  __shared__ float sBias[2176];   // window: n in [q0-2047, q0+128)
  __shared__ float sPen[2048];

  const int L = blockIdx.x;
  const int bh = (L & 7) * 4 + ((L >> 3) & 3);   // same-bh blocks -> same XCD
  const int qc = (L >> 5) & 15;
  const int half = (SPLIT == 2) ? (L >> 9) : 0;
  const int b = bh >> 4, h = bh & 15;
  const int t = threadIdx.x, w = t >> 6, lane = t & 63;
  const int lq = lane & 31, hi = lane >> 5;
  const int q0 = qc * 128;
  const int q0w = q0 + w * 32;
  const size_t base = (size_t)bh * LKK * DHEAD;

  for (int i = t; i < 2176; i += 256) {
    int n = i + q0 - 2047;
    n = n < 0 ? 0 : (n > 2047 ? 2047 : n);
    sBias[i] = BIASg[h * 2048 + n];
  }
  for (int i = t; i < 2048; i += 256)
    sPen[i] = M8[b * LKK + i] ? 0.0f : -3.0e9f;
  __syncthreads();

  // Q B-frags: lane holds Q[q=q0w+lq][d = s*16 + hi*8 .. +8]
  f16x8 qb[4];
  const f16* qrow = QH + base + (size_t)(q0w + lq) * DHEAD;
#pragma unroll
  for (int s = 0; s < 4; ++s)
    qb[s] = *(const f16x8*)(qrow + s * 16 + hi * 8);

  const f16* Kb = KH + base;
  const f16* Vb = VT + base;

  float m_r = -1e30f;
  f32x16 oacc0 = {}, oacc1 = {}, oaccL = {};
  const float c1 = 0.125f * LOG2E;
  f16x8 ones;
#pragma unroll
  for (int e = 0; e < 8; ++e) ones[e] = (f16)1.0f;

  const int kt0 = half * (32 / SPLIT);
  const int ktN = kt0 + 32 / SPLIT;
  for (int kt = kt0; kt < ktN; ++kt) {
    // S^T = K * Q^T, K frags straight from global (L2-resident)
    const f16* Kt = Kb + (size_t)kt * 64 * DHEAD;
    f32x16 sa0 = {}, sa1 = {};
    __builtin_amdgcn_s_setprio(1);
#pragma unroll
    for (int s = 0; s < 4; ++s) {
      f16x8 k0 = *(const f16x8*)(Kt + (size_t)lq * DHEAD + s * 16 + hi * 8);
      f16x8 k1 = *(const f16x8*)(Kt + (size_t)(32 + lq) * DHEAD + s * 16 + hi * 8);
      sa0 = MFMA32(k0, qb[s], sa0);
      sa1 = MFMA32(k1, qb[s], sa1);
    }
    __builtin_amdgcn_s_setprio(0);

    float p_[32];
#pragma unroll
    for (int r = 0; r < 16; ++r) { p_[r] = sa0[r]; p_[16 + r] = sa1[r]; }

    // scale + bias + mask penalty (log2 domain): k = kt*64 + tt*32 + j*8 + hi*4 + e
#pragma unroll
    for (int u = 0; u < 8; ++u) {
      int tt = u >> 2, j = u & 3;
      int kbase = kt * 64 + tt * 32 + j * 8 + hi * 4;
      f32x4 pen4 = *(const f32x4*)&sPen[kbase];
      int bidx0 = w * 32 + lq - kbase + 2047;
#pragma unroll
      for (int e = 0; e < 4; ++e) {
        float bp = sBias[bidx0 - e] + pen4[e];
        int r = tt * 16 + j * 4 + e;
        p_[r] = p_[r] * c1 + bp;
      }
    }

    // row max: max3 triples + cross-half exchange
    float mm[11];
#pragma unroll
    for (int r = 0; r < 10; ++r) mm[r] = fmax3(p_[3 * r], p_[3 * r + 1], p_[3 * r + 2]);
    mm[10] = fmaxf(p_[30], p_[31]);
    float a0 = fmax3(mm[0], mm[1], mm[2]);
    float a1 = fmax3(mm[3], mm[4], mm[5]);
    float a2 = fmax3(mm[6], mm[7], mm[8]);
    float a3 = fmax3(mm[9], mm[10], a0);
    float mx = fmax3(a1, a2, a3);
    mx = fmaxf(mx, __shfl_xor(mx, 32));

    // defer-max rescale (THR=8 in log2 domain)
    if (__any(mx > m_r + 8.0f)) {
      float mnew = fmaxf(m_r, mx);
      float al = ex2(m_r - mnew);
      m_r = mnew;
#pragma unroll
      for (int r = 0; r < 16; ++r) { oacc0[r] *= al; oacc1[r] *= al; oaccL[r] *= al; }
    }

#pragma unroll
    for (int r = 0; r < 32; ++r) p_[r] = ex2(p_[r] - m_r);

    // pack P -> f16 B-frags via cvt_pk + permlane32_swap
    f16x8 pf[4];
#pragma unroll
    for (int sl = 0; sl < 4; ++sl) {
      int tt = sl >> 1, sp = sl & 1;
      int bA = tt * 16 + (2 * sp) * 4, bB = tt * 16 + (2 * sp + 1) * 4;
      u32 A0 = pkr(p_[bA], p_[bA + 1]);
      u32 A1 = pkr(p_[bA + 2], p_[bA + 3]);
      u32 B0 = pkr(p_[bB], p_[bB + 1]);
      u32 B1 = pkr(p_[bB + 2], p_[bB + 3]);
      asm volatile("v_permlane32_swap_b32 %0, %1" : "+v"(A0), "+v"(B0));
      asm volatile("v_permlane32_swap_b32 %0, %1" : "+v"(A1), "+v"(B1));
      union { u32 u[4]; f16x8 v; } c;
      c.u[0] = A0; c.u[1] = A1; c.u[2] = B0; c.u[3] = B1;
      pf[sl] = c.v;
    }

    // O^T += V^T * P, V frags straight from global; l-row via ones-MFMA
    const f16* Vt = Vb + kt * 64;
    __builtin_amdgcn_s_setprio(1);
#pragma unroll
    for (int sl = 0; sl < 4; ++sl) {
      f16x8 v0 = *(const f16x8*)(Vt + (size_t)lq * LKK + sl * 16 + hi * 8);
      f16x8 v1 = *(const f16x8*)(Vt + (size_t)(32 + lq) * LKK + sl * 16 + hi * 8);
      oacc0 = MFMA32(v0, pf[sl], oacc0);
      oacc1 = MFMA32(v1, pf[sl], oacc1);
      oaccL = MFMA32(ones, pf[sl], oaccL);
    }
    __builtin_amdgcn_s_setprio(0);
  }

  const float l = oaccL[0];
  const float rinv = l > 0.0f ? 1.0f / l : 0.0f;
  if constexpr (SPLIT == 1) {
    const size_t orow = ((size_t)b * LQ + (q0w + lq)) * D_MODEL + h * DHEAD;
#pragma unroll
    for (int dh = 0; dh < 2; ++dh)
#pragma unroll
      for (int j = 0; j < 4; ++j) {
        int d0 = dh * 32 + j * 8 + hi * 4;
        f16x4 ov;
#pragma unroll
        for (int e = 0; e < 4; ++e)
          ov[e] = (f16)((dh ? oacc1[j * 4 + e] : oacc0[j * 4 + e]) * rinv);
        *(f16x4*)(OUT + orow + d0) = ov;
      }
  } else {
    const size_t row = (size_t)bh * 2048 + (q0w + lq);
    const size_t prow = ((size_t)half * 65536 + row) * 64;
#pragma unroll
    for (int dh = 0; dh < 2; ++dh)
#pragma unroll
      for (int j = 0; j < 4; ++j) {
        int d0 = dh * 32 + j * 8 + hi * 4;
        f16x4 ov;
#pragma unroll
        for (int e = 0; e < 4; ++e)
          ov[e] = (f16)((dh ? oacc1[j * 4 + e] : oacc0[j * 4 + e]) * rinv);
        *(f16x4*)(OUT + prow + d0) = ov;
      }
    if (hi == 0)
      ((float2*)ML)[half * 65536 + row] = make_float2(m_r, l);
  }
}

// combine two KV-split partials: O = (w0*O0 + w1*O1)/(w0+w1), w_i = exp2(m_i - M)*l_i
__global__ void k_combine(const f16* __restrict__ P16, const float* __restrict__ ML,
                          f16* __restrict__ O16) {
  const int idx = blockIdx.x * 256 + threadIdx.x;  // 524288
  const int row = idx >> 3;
  const int dg = (idx & 7) * 8;
  float2 ml0 = ((const float2*)ML)[row];
  float2 ml1 = ((const float2*)ML)[65536 + row];
  float M = fmaxf(ml0.x, ml1.x);
  float w0 = ex2(ml0.x - M) * ml0.y;
  float w1 = ex2(ml1.x - M) * ml1.y;
  float rd = 1.0f / (w0 + w1);
  w0 *= rd; w1 *= rd;
  f16x8 o0 = *(const f16x8*)(P16 + (size_t)row * 64 + dg);
  f16x8 o1 = *(const f16x8*)(P16 + ((size_t)65536 + row) * 64 + dg);
  const int bh = row >> 11, qq = row & 2047;
  const int b = bh >> 4, h = bh & 15;
  f16x8 ov;
#pragma unroll
  for (int e = 0; e < 8; ++e)
    ov[e] = (f16)(w0 * (float)o0[e] + w1 * (float)o1[e]);
  *(f16x8*)(O16 + ((size_t)b * LQ + qq) * D_MODEL + h * DHEAD + dg) = ov;
}

// ---------------- launch ----------------
extern "C" void kernel_launch(void* const* d_in, const int* in_sizes, int n_in,
                              void* d_out, int out_size, void* d_ws, size_t ws_size,
                              hipStream_t stream) {
  (void)in_sizes; (void)n_in; (void)out_size;
  const float* q   = (const float*)d_in[0];
  const float* k   = (const float*)d_in[1];
  const float* v   = (const float*)d_in[2];
  const void*  msk = d_in[3];
  const float* Wq  = (const float*)d_in[4];
  const float* Wk  = (const float*)d_in[5];
  const float* Wv  = (const float*)d_in[6];
  const float* Wo  = (const float*)d_in[7];
  const float* rel = (const float*)d_in[8];

  char* ws = (char*)d_ws;
  const size_t SL = (size_t)8 << 20;       // 8 MiB slabs
  f16* QHp = (f16*)(ws + 0 * SL);
  f16* KHp = (f16*)(ws + 1 * SL);
  f16* VTp = (f16*)(ws + 2 * SL);
  f16* O16 = (f16*)(ws + 3 * SL);
  f16* W16 = (f16*)(ws + 4 * SL);          // 4 x 1M f16 = 8 MB
  char* misc = ws + 5 * SL;
  float* BIAS = (float*)misc;              // 128 KB
  unsigned char* M8 = (unsigned char*)(misc + (192 << 10));
  f16* P16 = (f16*)(ws + 5 * SL + (1 << 20));    // 16 MB partials
  float* ML = (float*)(ws + 5 * SL + (17 << 20)); // 1 MB (m,l)
  const bool split2 = ws_size >= (size_t)(59 << 20);

  k_cvtw_prep<<<4098, 256, 0, stream>>>(Wq, Wk, Wv, Wo, W16, msk, rel, BIAS, M8);
  k_gemm_qkv<<<dim3(32, 8, 3), 256, 0, stream>>>(q, k, v, W16, QHp, KHp, VTp);
  if (split2) {
    k_attn<2><<<1024, 256, 0, stream>>>(QHp, KHp, VTp, BIAS, M8, P16, ML);
    k_combine<<<2048, 256, 0, stream>>>(P16, ML, O16);
  } else {
    k_attn<1><<<512, 256, 0, stream>>>(QHp, KHp, VTp, BIAS, M8, O16, nullptr);
  }
  k_gemm_o<<<dim3(32, 16), 256, 0, stream>>>(O16, W16 + 3 * 1048576, (float*)d_out);
}

// Round 8
// 188.306 us; speedup vs baseline: 1.2667x; 1.2667x over previous
//
#include <hip/hip_runtime.h>
#include <math.h>

typedef _Float16 f16;
typedef __fp16 h16x2 __attribute__((ext_vector_type(2)));
typedef _Float16 f16x4 __attribute__((ext_vector_type(4)));
typedef _Float16 f16x8 __attribute__((ext_vector_type(8)));
typedef float f32x4 __attribute__((ext_vector_type(4)));
typedef float f32x16 __attribute__((ext_vector_type(16)));
typedef unsigned int u32;

#define D_MODEL 1024
#define NHEADS 16
#define DHEAD 64
#define LQ 2048
#define LKK 2048
#define BB 2
#define LOG2E 1.4426950408889634f

static __device__ __forceinline__ void gload16(const void* g, void* l) {
  __builtin_amdgcn_global_load_lds(
      (const __attribute__((address_space(1))) u32*)g,
      (__attribute__((address_space(3))) u32*)l, 16, 0, 0);
}
static __device__ __forceinline__ float ex2(float x) {
  float r;
  asm volatile("v_exp_f32 %0, %1\n\ts_nop 0" : "=v"(r) : "v"(x));
  return r;
}
static __device__ __forceinline__ u32 pkr(float a, float b) {
  union { h16x2 h; u32 u; } c;
  c.h = __builtin_amdgcn_cvt_pkrtz(a, b);
  return c.u;
}
static __device__ __forceinline__ float fmax3(float a, float b, float c) {
  return fmaxf(fmaxf(a, b), c);  // clang fuses to v_max3_f32
}
#define MFMA16(a, b, c) __builtin_amdgcn_mfma_f32_16x16x32_f16(a, b, c, 0, 0, 0)
#define MFMA32(a, b, c) __builtin_amdgcn_mfma_f32_32x32x16_f16(a, b, c, 0, 0, 0)

// ---------------- W convert + prep (mask detect/convert, bias table) ----------------
__global__ void k_cvtw_prep(const float* Wq, const float* Wk, const float* Wv, const float* Wo,
                            f16* W16, const void* msk, const float* __restrict__ rel,
                            float* __restrict__ biasT, unsigned char* __restrict__ m8) {
  const int blk = blockIdx.x;
  const int t = threadIdx.x;
  if (blk < 4096) {  // W fp32->fp16: 4 x 1M elems = 1M float4
    int i = blk * 256 + t;
    int which = i >> 18, off = i & 262143;
    const float* s = which == 0 ? Wq : (which == 1 ? Wk : (which == 2 ? Wv : Wo));
    float4 x = ((const float4*)s)[off];
    f16x4 o; o[0] = (f16)x.x; o[1] = (f16)x.y; o[2] = (f16)x.z; o[3] = (f16)x.w;
    ((f16x4*)(W16 + (size_t)which * 1048576))[off] = o;
    return;
  }
  if (blk == 4096) {  // mask dtype detect + convert to u8
    __shared__ int o1s, o2s;
    if (t == 0) { o1s = 0; o2s = 0; }
    __syncthreads();
    const unsigned char* raw = (const unsigned char*)msk;
    int o1 = 0, o2 = 0;
    for (int i = t; i < BB * LKK; i += 256) {
      unsigned char vv = raw[i];
      if ((i & 3) && vv) o1 = 1;
      if (((i & 3) == 2) && vv == 0x80u) o2 = 1;
    }
    if (o1) atomicOr(&o1s, 1);
    if (o2) atomicOr(&o2s, 1);
    __syncthreads();
    const int f = o1s ? (o2s ? 2 : 1) : 0;  // 0=int32, 1=bool, 2=f32
    for (int i = t; i < BB * LKK; i += 256) {
      unsigned char v;
      if (f == 0)      v = (((const int*)msk)[i] != 0);
      else if (f == 1) v = (((const unsigned char*)msk)[i] != 0);
      else             v = (((const float*)msk)[i] != 0.0f);
      m8[i] = v;
    }
    return;
  }
  // blk == 4097: bias table, pre-scaled by log2e
  for (int n = t; n < 2048; n += 256) {
    int bucket;
    if (n < 16) bucket = n;
    else {
      float tt = logf((float)n / 16.0f + 1e-9f);  // exact jax op order
      tt = tt / 2.0794415416798357f;
      tt = tt * 16.0f;
      bucket = 16 + (int)tt;
      if (bucket > 31) bucket = 31;
    }
    for (int h = 0; h < NHEADS; ++h)
      biasT[h * 2048 + n] = rel[bucket * NHEADS + h] * LOG2E;
  }
}

// ---------------- GEMM core: C = A[4096,1024] * B[1024,1024]^T, tile 128 x BN ----------------
// Double-buffered LDS, ONE barrier per K-step; AF32: A fp32 reg-staged (loads issued at
// phase start, latency covered by the MFMA phase), fused RTE cvt.
// EPI 0: f16 scatter [B,H,L,64].  EPI 1: fp32 row-major.  EPI 2: f16 V^T [B,H,64,L].
template <int EPI, int BN, bool AF32>
static __device__ __forceinline__ void gemm_core(const void* __restrict__ Av,
                                                 const f16* __restrict__ Bm,
                                                 void* __restrict__ C) {
  constexpr int JN = BN / 32;  // col frags per wave
  __shared__ __align__(16) f16 sA[2][128 * 32];
  __shared__ __align__(16) f16 sB[2][BN * 32];
  const int t = threadIdx.x;
  const int w = t >> 6, lane = t & 63;
  const int lg = lane >> 4, lc = lane & 15;
  const int wr = w >> 1, wc = w & 1;
  const long row0 = (long)blockIdx.x * 128;
  const long col0 = (long)blockIdx.y * BN;
  f32x4 acc[4][JN] = {};

  const int rA0 = t >> 2, kA0 = t & 3;           // chunk t
  const int rA1 = (t + 256) >> 2, kA1 = t & 3;   // chunk t+256

  float4 a[4];  // reg stage for AF32 (2 chunks x 2 float4)

  auto LOADA = [&](int kk) {
    const float* s0 = (const float*)Av + (row0 + rA0) * 1024 + kk * 32 + kA0 * 8;
    const float* s1 = (const float*)Av + (row0 + rA1) * 1024 + kk * 32 + kA1 * 8;
    a[0] = *(const float4*)s0; a[1] = *(const float4*)(s0 + 4);
    a[2] = *(const float4*)s1; a[3] = *(const float4*)(s1 + 4);
  };
  auto WRITEA = [&](int buf) {
    f16x8 o0, o1;
    o0[0] = (f16)a[0].x; o0[1] = (f16)a[0].y; o0[2] = (f16)a[0].z; o0[3] = (f16)a[0].w;
    o0[4] = (f16)a[1].x; o0[5] = (f16)a[1].y; o0[6] = (f16)a[1].z; o0[7] = (f16)a[1].w;
    o1[0] = (f16)a[2].x; o1[1] = (f16)a[2].y; o1[2] = (f16)a[2].z; o1[3] = (f16)a[2].w;
    o1[4] = (f16)a[3].x; o1[5] = (f16)a[3].y; o1[6] = (f16)a[3].z; o1[7] = (f16)a[3].w;
    *(f16x8*)((char*)&sA[buf][0] + t * 16) = o0;
    *(f16x8*)((char*)&sA[buf][0] + (t + 256) * 16) = o1;
  };
  auto STAGEA16 = [&](int kk, int buf) {
    gload16((const f16*)Av + (row0 + rA0) * 1024 + kk * 32 + kA0 * 8,
            (char*)&sA[buf][0] + t * 16);
    gload16((const f16*)Av + (row0 + rA1) * 1024 + kk * 32 + kA1 * 8,
            (char*)&sA[buf][0] + (t + 256) * 16);
  };
  auto STAGEB = [&](int kk, int buf) {
#pragma unroll
    for (int it = 0; it < BN / 64; ++it) {
      int ch = t + it * 256;
      int r = ch >> 2, kq = ch & 3;
      gload16(Bm + (col0 + r) * 1024 + kk * 32 + kq * 8, (char*)&sB[buf][0] + ch * 16);
    }
  };
  auto COMPUTE = [&](int buf) {
    f16x8 af[4], bf[JN];
#pragma unroll
    for (int i = 0; i < 4; ++i)
      af[i] = *(const f16x8*)&sA[buf][(wr * 64 + i * 16 + lc) * 32 + lg * 8];
#pragma unroll
    for (int j = 0; j < JN; ++j)
      bf[j] = *(const f16x8*)&sB[buf][(wc * (16 * JN) + j * 16 + lc) * 32 + lg * 8];
#pragma unroll
    for (int i = 0; i < 4; ++i)
#pragma unroll
      for (int j = 0; j < JN; ++j)
        acc[i][j] = MFMA16(af[i], bf[j], acc[i][j]);
  };

  // prologue: stage K-step 0 into buf 0
  if constexpr (AF32) { LOADA(0); } else { STAGEA16(0, 0); }
  STAGEB(0, 0);
  if constexpr (AF32) WRITEA(0);
  __syncthreads();

  for (int kk = 0; kk < 32; ++kk) {
    const int cur = kk & 1;
    if (kk < 31) {  // issue next-step loads BEFORE compute (latency hides under MFMA)
      if constexpr (AF32) { LOADA(kk + 1); } else { STAGEA16(kk + 1, cur ^ 1); }
      STAGEB(kk + 1, cur ^ 1);
    }
    COMPUTE(cur);
    if (kk < 31) { if constexpr (AF32) WRITEA(cur ^ 1); }
    __syncthreads();
  }

#pragma unroll
  for (int i = 0; i < 4; ++i)
#pragma unroll
    for (int j = 0; j < JN; ++j) {
      const long rowb = row0 + wr * 64 + i * 16 + lg * 4;
      const long col = col0 + wc * (16 * JN) + j * 16 + lc;
      if (EPI == 2) {  // V^T: [b,h,d,l] with f16x4 over l
        long b = rowb >> 11, l0 = rowb & 2047;
        long h = col >> 6, d = col & 63;
        f16x4 ov;
#pragma unroll
        for (int r = 0; r < 4; ++r) ov[r] = (f16)acc[i][j][r];
        *(f16x4*)((f16*)C + (((b * NHEADS + h) * DHEAD + d) * (long)LKK + l0)) = ov;
      } else {
#pragma unroll
        for (int r = 0; r < 4; ++r) {
          long row = rowb + r;
          float v = acc[i][j][r];
          if (EPI == 0) {
            long b = row >> 11, l = row & 2047;
            long h = col >> 6, d = col & 63;
            ((f16*)C)[(((b * NHEADS + h) * LQ) + l) * DHEAD + d] = (f16)v;
          } else {
            ((float*)C)[row * 1024 + col] = v;
          }
        }
      }
    }
}

__global__ void __launch_bounds__(256, 3)
k_gemm_qkv(const float* __restrict__ q, const float* __restrict__ k, const float* __restrict__ v,
           const f16* __restrict__ W16, f16* __restrict__ QHp, f16* __restrict__ KHp,
           f16* __restrict__ VTp) {
  const int z = blockIdx.z;
  if (z == 2) {
    gemm_core<2, 128, true>(v, W16 + 2 * 1048576, VTp);
  } else {
    const float* A = z == 0 ? q : k;
    f16* C = z == 0 ? QHp : KHp;
    gemm_core<0, 128, true>(A, W16 + (size_t)z * 1048576, C);
  }
}

__global__ void __launch_bounds__(256, 2)
k_gemm_o(const f16* __restrict__ A, const f16* __restrict__ Bm, float* __restrict__ C) {
  gemm_core<1, 64, false>(A, Bm, C);
}

// ---------------- flash attention: LDS-staged K/V, KV-split for occupancy ----------------
// 4 warps/block, 32 q-rows/warp. SPLIT=2: grid 1024 = 4 blocks/CU, each block does half the
// KV range (16 tiles), writes normalized partial O (f16) + (m,l); combine merges.
// LDS: K/V double-buffered (32KB) + windowed bias (4.6KB) + f16 mask penalty (2KB) = 39.4KB.
template <int SPLIT>
__global__ void __launch_bounds__(256, 4)
k_attn(const f16* __restrict__ QH, const f16* __restrict__ KH, const f16* __restrict__ VT,
       const float* __restrict__ BIASg, const unsigned char* __restrict__ M8,
       f16* __restrict__ OUT, float* __restrict__ ML) {
  constexpr int KR = LKK / SPLIT;          // k-range per block
  constexpr int NT = KR / 64;              // tiles per block
  __shared__ __align__(16) f16 sK[2][64 * 64];
  __shared__ __align__(16) f16 sVT[2][64 * 64];
  __shared__ __align__(16) float sBias[KR + 128];  // window n in [q0-KR+1, q0+128)
  __shared__ __align__(16) f16 sPen[KR + 8];       // 0 or -60000 (log2 domain)

  const int L = blockIdx.x;
  const int bh = (L & 7) * 4 + ((L >> 3) & 3);     // same-bh blocks -> same XCD
  const int qc = (L >> 5) & 15;
  const int half = (SPLIT == 2) ? (L >> 9) : 0;
  const int b = bh >> 4, h = bh & 15;
  const int t = threadIdx.x, w = t >> 6, lane = t & 63;
  const int lq = lane & 31, hi = lane >> 5;
  const int q0 = qc * 128;
  const int q0w = q0 + w * 32;
  const int kt0 = half * NT;
  const size_t base = (size_t)bh * LKK * DHEAD;

  for (int i = t; i < KR + 128; i += 256) {
    int n = i - (KR - 1) + q0 - kt0 * 64;
    n = n < 0 ? 0 : (n > 2047 ? 2047 : n);
    sBias[i] = BIASg[h * 2048 + n];
  }
  for (int i = t; i < KR; i += 256)
    sPen[i] = M8[b * LKK + kt0 * 64 + i] ? (f16)0.0f : (f16)-60000.0f;

  // Q B-frags: lane holds Q[q=q0w+lq][d = s*16 + hi*8 .. +8]
  f16x8 qb[4];
  const f16* qrow = QH + base + (size_t)(q0w + lq) * DHEAD;
#pragma unroll
  for (int s = 0; s < 4; ++s)
    qb[s] = *(const f16x8*)(qrow + s * 16 + hi * 8);

  // per-thread staging geometry (identical for K rows and V^T rows)
  const int ch0 = t, ch1 = t + 256;
  const int r0 = ch0 >> 3, g0 = ((ch0 & 7) ^ (r0 & 7)) * 8;
  const int r1 = ch1 >> 3, g1 = ((ch1 & 7) ^ (r1 & 7)) * 8;
  const f16* Kb = KH + base;
  const f16* Vb = VT + base;

  auto STAGE = [&](int kt, int buf) {
    const int k0 = kt * 64;
    gload16(Kb + (size_t)(k0 + r0) * DHEAD + g0, (char*)&sK[buf][0] + ch0 * 16);
    gload16(Kb + (size_t)(k0 + r1) * DHEAD + g1, (char*)&sK[buf][0] + ch1 * 16);
    gload16(Vb + (size_t)r0 * LKK + k0 + g0, (char*)&sVT[buf][0] + ch0 * 16);
    gload16(Vb + (size_t)r1 * LKK + k0 + g1, (char*)&sVT[buf][0] + ch1 * 16);
  };

  float m_r = -1e30f;
  f32x16 oacc0 = {}, oacc1 = {}, oaccL = {};
  const float c1 = 0.125f * LOG2E;
  f16x8 ones;
#pragma unroll
  for (int e = 0; e < 8; ++e) ones[e] = (f16)1.0f;

  STAGE(kt0, 0);
  __syncthreads();

  for (int it = 0; it < NT; ++it) {
    const int kt = kt0 + it;
    const int cur = it & 1;
    if (it + 1 < NT) STAGE(kt + 1, cur ^ 1);

    // S^T = K * Q^T : lane owns q-col lq; rows = k
    const char* sKb = (const char*)&sK[cur][0];
    f32x16 sa0 = {}, sa1 = {};
    __builtin_amdgcn_s_setprio(1);
#pragma unroll
    for (int s = 0; s < 4; ++s) {
      f16x8 k0 = *(const f16x8*)(sKb + ((lq * 128 + s * 32 + hi * 16) ^ ((lq & 7) << 4)));
      f16x8 k1 = *(const f16x8*)(sKb + (((32 + lq) * 128 + s * 32 + hi * 16) ^ ((lq & 7) << 4)));
      sa0 = MFMA32(k0, qb[s], sa0);
      sa1 = MFMA32(k1, qb[s], sa1);
    }
    __builtin_amdgcn_s_setprio(0);

    float p_[32];
#pragma unroll
    for (int r = 0; r < 16; ++r) { p_[r] = sa0[r]; p_[16 + r] = sa1[r]; }

    // scale + bias + mask penalty (log2 domain): klocal = it*64 + tt*32 + j*8 + hi*4 + e
#pragma unroll
    for (int u = 0; u < 8; ++u) {
      int tt = u >> 2, j = u & 3;
      int kloc = it * 64 + tt * 32 + j * 8 + hi * 4;
      f16x4 pen4 = *(const f16x4*)&sPen[kloc];
      int bidx0 = w * 32 + lq - kloc + (KR - 1);
#pragma unroll
      for (int e = 0; e < 4; ++e) {
        float bp = sBias[bidx0 - e] + (float)pen4[e];
        int r = tt * 16 + j * 4 + e;
        p_[r] = p_[r] * c1 + bp;
      }
    }

    // row max: max3 triples + cross-half exchange
    float mm[11];
#pragma unroll
    for (int r = 0; r < 10; ++r) mm[r] = fmax3(p_[3 * r], p_[3 * r + 1], p_[3 * r + 2]);
    mm[10] = fmaxf(p_[30], p_[31]);
    float a0 = fmax3(mm[0], mm[1], mm[2]);
    float a1 = fmax3(mm[3], mm[4], mm[5]);
    float a2 = fmax3(mm[6], mm[7], mm[8]);
    float a3 = fmax3(mm[9], mm[10], a0);
    float mx = fmax3(a1, a2, a3);
    mx = fmaxf(mx, __shfl_xor(mx, 32));

    // defer-max rescale (THR=8 in log2 domain)
    if (__any(mx > m_r + 8.0f)) {
      float mnew = fmaxf(m_r, mx);
      float al = ex2(m_r - mnew);
      m_r = mnew;
#pragma unroll
      for (int r = 0; r < 16; ++r) { oacc0[r] *= al; oacc1[r] *= al; oaccL[r] *= al; }
    }

#pragma unroll
    for (int r = 0; r < 32; ++r) p_[r] = ex2(p_[r] - m_r);

    // pack P -> f16 B-frags via cvt_pk + permlane32_swap (T12)
    f16x8 pf[4];
#pragma unroll
    for (int sl = 0; sl < 4; ++sl) {
      int tt = sl >> 1, sp = sl & 1;
      int bA = tt * 16 + (2 * sp) * 4, bB = tt * 16 + (2 * sp + 1) * 4;
      u32 A0 = pkr(p_[bA], p_[bA + 1]);
      u32 A1 = pkr(p_[bA + 2], p_[bA + 3]);
      u32 B0 = pkr(p_[bB], p_[bB + 1]);
      u32 B1 = pkr(p_[bB + 2], p_[bB + 3]);
      asm volatile("v_permlane32_swap_b32 %0, %1" : "+v"(A0), "+v"(B0));
      asm volatile("v_permlane32_swap_b32 %0, %1" : "+v"(A1), "+v"(B1));
      union { u32 u[4]; f16x8 v; } c;
      c.u[0] = A0; c.u[1] = A1; c.u[2] = B0; c.u[3] = B1;
      pf[sl] = c.v;
    }

    // O^T += V^T * P (rows = d); l-row via ones-MFMA on the matrix pipe
    const char* sVb = (const char*)&sVT[cur][0];
    __builtin_amdgcn_s_setprio(1);
#pragma unroll
    for (int sl = 0; sl < 4; ++sl) {
      int K0 = sl * 16;
      f16x8 v0 = *(const f16x8*)(sVb + ((lq * 128 + K0 * 2 + hi * 16) ^ ((lq & 7) << 4)));
      f16x8 v1 = *(const f16x8*)(sVb + (((32 + lq) * 128 + K0 * 2 + hi * 16) ^ ((lq & 7) << 4)));
      oacc0 = MFMA32(v0, pf[sl], oacc0);
      oacc1 = MFMA32(v1, pf[sl], oacc1);
      oaccL = MFMA32(ones, pf[sl], oaccL);
    }
    __builtin_amdgcn_s_setprio(0);
    __syncthreads();
  }

  const float l = oaccL[0];
  const float rinv = l > 0.0f ? 1.0f / l : 0.0f;
  if constexpr (SPLIT == 1) {
    const size_t orow = ((size_t)b * LQ + (q0w + lq)) * D_MODEL + h * DHEAD;
#pragma unroll
    for (int dh = 0; dh < 2; ++dh)
#pragma unroll
      for (int j = 0; j < 4; ++j) {
        int d0 = dh * 32 + j * 8 + hi * 4;
        f16x4 ov;
#pragma unroll
        for (int e = 0; e < 4; ++e)
          ov[e] = (f16)((dh ? oacc1[j * 4 + e] : oacc0[j * 4 + e]) * rinv);
        *(f16x4*)(OUT + orow + d0) = ov;
      }
  } else {
    const size_t row = (size_t)bh * 2048 + (q0w + lq);
    const size_t prow = ((size_t)half * 65536 + row) * 64;
#pragma unroll
    for (int dh = 0; dh < 2; ++dh)
#pragma unroll
      for (int j = 0; j < 4; ++j) {
        int d0 = dh * 32 + j * 8 + hi * 4;
        f16x4 ov;
#pragma unroll
        for (int e = 0; e < 4; ++e)
          ov[e] = (f16)((dh ? oacc1[j * 4 + e] : oacc0[j * 4 + e]) * rinv);
        *(f16x4*)(OUT + prow + d0) = ov;
      }
    if (hi == 0)
      ((float2*)ML)[half * 65536 + row] = make_float2(m_r, l);
  }
}

// combine two KV-split partials: O = (w0*O0 + w1*O1)/(w0+w1), w_i = exp2(m_i - M)*l_i
__global__ void k_combine(const f16* __restrict__ P16, const float* __restrict__ ML,
                          f16* __restrict__ O16) {
  const int idx = blockIdx.x * 256 + threadIdx.x;  // 524288
  const int row = idx >> 3;
  const int dg = (idx & 7) * 8;
  float2 ml0 = ((const float2*)ML)[row];
  float2 ml1 = ((const float2*)ML)[65536 + row];
  float M = fmaxf(ml0.x, ml1.x);
  float w0 = ex2(ml0.x - M) * ml0.y;
  float w1 = ex2(ml1.x - M) * ml1.y;
  float rd = 1.0f / (w0 + w1);
  w0 *= rd; w1 *= rd;
  f16x8 o0 = *(const f16x8*)(P16 + (size_t)row * 64 + dg);
  f16x8 o1 = *(const f16x8*)(P16 + ((size_t)65536 + row) * 64 + dg);
  const int bh = row >> 11, qq = row & 2047;
  const int b = bh >> 4, h = bh & 15;
  f16x8 ov;
#pragma unroll
  for (int e = 0; e < 8; ++e)
    ov[e] = (f16)(w0 * (float)o0[e] + w1 * (float)o1[e]);
  *(f16x8*)(O16 + ((size_t)b * LQ + qq) * D_MODEL + h * DHEAD + dg) = ov;
}

// ---------------- launch ----------------
extern "C" void kernel_launch(void* const* d_in, const int* in_sizes, int n_in,
                              void* d_out, int out_size, void* d_ws, size_t ws_size,
                              hipStream_t stream) {
  (void)in_sizes; (void)n_in; (void)out_size;
  const float* q   = (const float*)d_in[0];
  const float* k   = (const float*)d_in[1];
  const float* v   = (const float*)d_in[2];
  const void*  msk = d_in[3];
  const float* Wq  = (const float*)d_in[4];
  const float* Wk  = (const float*)d_in[5];
  const float* Wv  = (const float*)d_in[6];
  const float* Wo  = (const float*)d_in[7];
  const float* rel = (const float*)d_in[8];

  char* ws = (char*)d_ws;
  const size_t SL = (size_t)8 << 20;       // 8 MiB slabs
  f16* QHp = (f16*)(ws + 0 * SL);
  f16* KHp = (f16*)(ws + 1 * SL);
  f16* VTp = (f16*)(ws + 2 * SL);
  f16* O16 = (f16*)(ws + 3 * SL);
  f16* W16 = (f16*)(ws + 4 * SL);          // 4 x 1M f16 = 8 MB
  char* misc = ws + 5 * SL;
  float* BIAS = (float*)misc;              // 128 KB
  unsigned char* M8 = (unsigned char*)(misc + (192 << 10));
  f16* P16 = (f16*)(ws + 5 * SL + (1 << 20));     // 16 MB partials
  float* ML = (float*)(ws + 5 * SL + (17 << 20)); // 1 MB (m,l)
  const bool split2 = ws_size >= (size_t)(59 << 20);

  k_cvtw_prep<<<4098, 256, 0, stream>>>(Wq, Wk, Wv, Wo, W16, msk, rel, BIAS, M8);
  k_gemm_qkv<<<dim3(32, 8, 3), 256, 0, stream>>>(q, k, v, W16, QHp, KHp, VTp);
  if (split2) {
    k_attn<2><<<1024, 256, 0, stream>>>(QHp, KHp, VTp, BIAS, M8, P16, ML);
    k_combine<<<2048, 256, 0, stream>>>(P16, ML, O16);
  } else {
    k_attn<1><<<512, 256, 0, stream>>>(QHp, KHp, VTp, BIAS, M8, O16, nullptr);
  }
  k_gemm_o<<<dim3(32, 16), 256, 0, stream>>>(O16, W16 + 3 * 1048576, (float*)d_out);
}

// Round 10
// 162.810 us; speedup vs baseline: 1.4651x; 1.1566x over previous
//
#include <hip/hip_runtime.h>
#include <math.h>

typedef _Float16 f16;
typedef __fp16 h16x2 __attribute__((ext_vector_type(2)));
typedef _Float16 f16x4 __attribute__((ext_vector_type(4)));
typedef _Float16 f16x8 __attribute__((ext_vector_type(8)));
typedef float f32x4 __attribute__((ext_vector_type(4)));
typedef float f32x16 __attribute__((ext_vector_type(16)));
typedef unsigned int u32;

#define D_MODEL 1024
#define NHEADS 16
#define DHEAD 64
#define LQ 2048
#define LKK 2048
#define BB 2
#define LOG2E 1.4426950408889634f

static __device__ __forceinline__ void gload16(const void* g, void* l) {
  __builtin_amdgcn_global_load_lds(
      (const __attribute__((address_space(1))) u32*)g,
      (__attribute__((address_space(3))) u32*)l, 16, 0, 0);
}
static __device__ __forceinline__ float ex2(float x) {
  float r;
  asm volatile("v_exp_f32 %0, %1\n\ts_nop 0" : "=v"(r) : "v"(x));
  return r;
}
static __device__ __forceinline__ u32 pkr(float a, float b) {
  union { h16x2 h; u32 u; } c;
  c.h = __builtin_amdgcn_cvt_pkrtz(a, b);
  return c.u;
}
static __device__ __forceinline__ float fmax3(float a, float b, float c) {
  return fmaxf(fmaxf(a, b), c);
}
#define MFMA16(a, b, c) __builtin_amdgcn_mfma_f32_16x16x32_f16(a, b, c, 0, 0, 0)
#define MFMA32(a, b, c) __builtin_amdgcn_mfma_f32_32x32x16_f16(a, b, c, 0, 0, 0)

// ---------------- merged convert (q,k,v,W -> f16) + prep (mask, bias table) ----------------
__global__ void k_cvt_prep(const float* q, const float* k, const float* v,
                           const float* Wq, const float* Wk, const float* Wv, const float* Wo,
                           f16* Xq, f16* Xk, f16* Xv, f16* W16,
                           const void* msk, const float* __restrict__ rel,
                           float* __restrict__ biasT, unsigned char* __restrict__ m8) {
  const int blk = blockIdx.x;
  const int t = threadIdx.x;
  if (blk < 16384) {  // 4M float4: 3M for q,k,v + 1M for W
    int i = blk * 256 + t;
    const float* s; f16* d; int off;
    if (i < 3145728) {
      int which = i >> 20; off = i & 1048575;
      s = which == 0 ? q : (which == 1 ? k : v);
      d = which == 0 ? Xq : (which == 1 ? Xk : Xv);
    } else {
      int j = i - 3145728; int which = j >> 18; off = j & 262143;
      s = which == 0 ? Wq : (which == 1 ? Wk : (which == 2 ? Wv : Wo));
      d = W16 + which * 1048576;
    }
    float4 x = ((const float4*)s)[off];
    f16x4 o; o[0] = (f16)x.x; o[1] = (f16)x.y; o[2] = (f16)x.z; o[3] = (f16)x.w;
    ((f16x4*)d)[off] = o;
    return;
  }
  if (blk == 16384) {  // mask dtype detect + convert to u8
    __shared__ int o1s, o2s;
    if (t == 0) { o1s = 0; o2s = 0; }
    __syncthreads();
    const unsigned char* raw = (const unsigned char*)msk;
    int o1 = 0, o2 = 0;
    for (int i = t; i < BB * LKK; i += 256) {
      unsigned char vv = raw[i];
      if ((i & 3) && vv) o1 = 1;
      if (((i & 3) == 2) && vv == 0x80u) o2 = 1;
    }
    if (o1) atomicOr(&o1s, 1);
    if (o2) atomicOr(&o2s, 1);
    __syncthreads();
    const int f = o1s ? (o2s ? 2 : 1) : 0;  // 0=int32, 1=bool, 2=f32
    for (int i = t; i < BB * LKK; i += 256) {
      unsigned char vv;
      if (f == 0)      vv = (((const int*)msk)[i] != 0);
      else if (f == 1) vv = (((const unsigned char*)msk)[i] != 0);
      else             vv = (((const float*)msk)[i] != 0.0f);
      m8[i] = vv;
    }
    return;
  }
  // blk == 16385: bias table, pre-scaled by log2e
  for (int n = t; n < 2048; n += 256) {
    int bucket;
    if (n < 16) bucket = n;
    else {
      float tt = logf((float)n / 16.0f + 1e-9f);  // exact jax op order
      tt = tt / 2.0794415416798357f;
      tt = tt * 16.0f;
      bucket = 16 + (int)tt;
      if (bucket > 31) bucket = 31;
    }
    for (int h = 0; h < NHEADS; ++h)
      biasT[h * 2048 + n] = rel[bucket * NHEADS + h] * LOG2E;
  }
}

// ---------------- GEMM core: C = A[4096,1024] * B[1024,1024]^T, tile 128 x BN ----------------
// f16 inputs, gload_lds staging, double-buffered LDS, ONE barrier per K-step.
// sA layout: 2 buffers x 4096 f16 (8192 B each). sB: 2 buffers x BN*32 f16 (BN*64 B each).
// EPI 0: f16 scatter [B,H,L,64].  EPI 1: fp32 row-major.  EPI 2: f16 V^T [B,H,64,L].
template <int EPI, int BN>
static __device__ __forceinline__ void gemm_core(const f16* __restrict__ A,
                                                 const f16* __restrict__ Bm,
                                                 void* __restrict__ C,
                                                 f16* sA, f16* sB) {
  constexpr int JN = BN / 32;  // col frags per wave
  const int t = threadIdx.x;
  const int w = t >> 6, lane = t & 63;
  const int lg = lane >> 4, lc = lane & 15;
  const int wr = w >> 1, wc = w & 1;
  const long row0 = (long)blockIdx.x * 128;
  const long col0 = (long)blockIdx.y * BN;
  f32x4 acc[4][JN] = {};

  const int rA0 = t >> 2, kA0 = t & 3;
  const int rA1 = (t + 256) >> 2;

  auto STAGEA = [&](int kk, int buf) {
    // per-buffer stride: 128*32 f16 = 8192 BYTES
    gload16(A + (row0 + rA0) * 1024 + kk * 32 + kA0 * 8, (char*)sA + buf * 8192 + t * 16);
    gload16(A + (row0 + rA1) * 1024 + kk * 32 + kA0 * 8,
            (char*)sA + buf * 8192 + (t + 256) * 16);
  };
  auto STAGEB = [&](int kk, int buf) {
#pragma unroll
    for (int it = 0; it < BN / 64; ++it) {
      int ch = t + it * 256;
      int r = ch >> 2, kq = ch & 3;
      gload16(Bm + (col0 + r) * 1024 + kk * 32 + kq * 8, (char*)sB + buf * BN * 64 + ch * 16);
    }
  };
  auto COMPUTE = [&](int buf) {
    f16x8 af[4], bf[JN];
#pragma unroll
    for (int i = 0; i < 4; ++i)
      af[i] = *(const f16x8*)&sA[buf * 4096 + (wr * 64 + i * 16 + lc) * 32 + lg * 8];
#pragma unroll
    for (int j = 0; j < JN; ++j)
      bf[j] = *(const f16x8*)&sB[buf * BN * 32 + (wc * (16 * JN) + j * 16 + lc) * 32 + lg * 8];
#pragma unroll
    for (int i = 0; i < 4; ++i)
#pragma unroll
      for (int j = 0; j < JN; ++j)
        acc[i][j] = MFMA16(af[i], bf[j], acc[i][j]);
  };

  STAGEA(0, 0);
  STAGEB(0, 0);
  __syncthreads();

  for (int kk = 0; kk < 32; ++kk) {
    const int cur = kk & 1;
    if (kk < 31) {  // issue next-step loads BEFORE compute; latency hides under MFMA
      STAGEA(kk + 1, cur ^ 1);
      STAGEB(kk + 1, cur ^ 1);
    }
    COMPUTE(cur);
    __syncthreads();
  }

#pragma unroll
  for (int i = 0; i < 4; ++i)
#pragma unroll
    for (int j = 0; j < JN; ++j) {
      const long rowb = row0 + wr * 64 + i * 16 + lg * 4;
      const long col = col0 + wc * (16 * JN) + j * 16 + lc;
      if (EPI == 2) {  // V^T: [b,h,d,l] with f16x4 over l
        long b = rowb >> 11, l0 = rowb & 2047;
        long h = col >> 6, d = col & 63;
        f16x4 ov;
#pragma unroll
        for (int r = 0; r < 4; ++r) ov[r] = (f16)acc[i][j][r];
        *(f16x4*)((f16*)C + (((b * NHEADS + h) * DHEAD + d) * (long)LKK + l0)) = ov;
      } else {
#pragma unroll
        for (int r = 0; r < 4; ++r) {
          long row = rowb + r;
          float vv = acc[i][j][r];
          if (EPI == 0) {
            long b = row >> 11, l = row & 2047;
            long h = col >> 6, d = col & 63;
            ((f16*)C)[(((b * NHEADS + h) * LQ) + l) * DHEAD + d] = (f16)vv;
          } else {
            ((float*)C)[row * 1024 + col] = vv;
          }
        }
      }
    }
}

__global__ void __launch_bounds__(256, 3)
k_gemm_qkv(const f16* __restrict__ Xq, const f16* __restrict__ Xk, const f16* __restrict__ Xv,
           const f16* __restrict__ W16, f16* __restrict__ QHp, f16* __restrict__ KHp,
           f16* __restrict__ VTp) {
  __shared__ __align__(16) f16 smem[2 * 128 * 32 + 2 * 128 * 32];  // 32 KB shared by branches
  f16* sA = smem;          // 8192 f16 (2 bufs x 4096)
  f16* sB = smem + 8192;   // 8192 f16 (2 bufs x 4096)
  const int z = blockIdx.z;
  if (z == 2) {
    gemm_core<2, 128>(Xv, W16 + 2 * 1048576, VTp, sA, sB);
  } else {
    const f16* A = z == 0 ? Xq : Xk;
    f16* C = z == 0 ? QHp : KHp;
    gemm_core<0, 128>(A, W16 + (size_t)z * 1048576, C, sA, sB);
  }
}

__global__ void __launch_bounds__(256, 2)
k_gemm_o(const f16* __restrict__ A, const f16* __restrict__ Bm, float* __restrict__ C) {
  __shared__ __align__(16) f16 smem[2 * 128 * 32 + 2 * 64 * 32];  // 24 KB
  gemm_core<1, 64>(A, Bm, C, smem, smem + 8192);
}

// ---------------- flash attention: LDS-staged K/V, KV-split for occupancy ----------------
// 4 warps/block, 32 q-rows/warp. SPLIT=2: grid 1024 = 4 blocks/CU, each block does half the
// KV range (16 tiles), writes normalized partial O (f16) + (m,l); combine merges.
// LDS: K/V double-buffered (32KB) + windowed bias (4.6KB) + f16 mask penalty (2KB) = 39.4KB.
template <int SPLIT>
__global__ void __launch_bounds__(256, 4)
k_attn(const f16* __restrict__ QH, const f16* __restrict__ KH, const f16* __restrict__ VT,
       const float* __restrict__ BIASg, const unsigned char* __restrict__ M8,
       f16* __restrict__ OUT, float* __restrict__ ML) {
  constexpr int KR = LKK / SPLIT;
  constexpr int NT = KR / 64;
  __shared__ __align__(16) f16 sK[2][64 * 64];
  __shared__ __align__(16) f16 sVT[2][64 * 64];
  __shared__ __align__(16) float sBias[KR + 128];
  __shared__ __align__(16) f16 sPen[KR + 8];

  const int L = blockIdx.x;
  const int bh = (L & 7) * 4 + ((L >> 3) & 3);
  const int qc = (L >> 5) & 15;
  const int half = (SPLIT == 2) ? (L >> 9) : 0;
  const int b = bh >> 4, h = bh & 15;
  const int t = threadIdx.x, w = t >> 6, lane = t & 63;
  const int lq = lane & 31, hi = lane >> 5;
  const int q0 = qc * 128;
  const int q0w = q0 + w * 32;
  const int kt0 = half * NT;
  const size_t base = (size_t)bh * LKK * DHEAD;

  for (int i = t; i < KR + 128; i += 256) {
    int n = i - (KR - 1) + q0 - kt0 * 64;
    n = n < 0 ? 0 : (n > 2047 ? 2047 : n);
    sBias[i] = BIASg[h * 2048 + n];
  }
  for (int i = t; i < KR; i += 256)
    sPen[i] = M8[b * LKK + kt0 * 64 + i] ? (f16)0.0f : (f16)-60000.0f;

  f16x8 qb[4];
  const f16* qrow = QH + base + (size_t)(q0w + lq) * DHEAD;
#pragma unroll
  for (int s = 0; s < 4; ++s)
    qb[s] = *(const f16x8*)(qrow + s * 16 + hi * 8);

  const int ch0 = t, ch1 = t + 256;
  const int r0 = ch0 >> 3, g0 = ((ch0 & 7) ^ (r0 & 7)) * 8;
  const int r1 = ch1 >> 3, g1 = ((ch1 & 7) ^ (r1 & 7)) * 8;
  const f16* Kb = KH + base;
  const f16* Vb = VT + base;

  auto STAGE = [&](int kt, int buf) {
    const int k0 = kt * 64;
    gload16(Kb + (size_t)(k0 + r0) * DHEAD + g0, (char*)&sK[buf][0] + ch0 * 16);
    gload16(Kb + (size_t)(k0 + r1) * DHEAD + g1, (char*)&sK[buf][0] + ch1 * 16);
    gload16(Vb + (size_t)r0 * LKK + k0 + g0, (char*)&sVT[buf][0] + ch0 * 16);
    gload16(Vb + (size_t)r1 * LKK + k0 + g1, (char*)&sVT[buf][0] + ch1 * 16);
  };

  float m_r = -1e30f;
  f32x16 oacc0 = {}, oacc1 = {}, oaccL = {};
  const float c1 = 0.125f * LOG2E;
  f16x8 ones;
#pragma unroll
  for (int e = 0; e < 8; ++e) ones[e] = (f16)1.0f;

  STAGE(kt0, 0);
  __syncthreads();

  for (int it = 0; it < NT; ++it) {
    const int kt = kt0 + it;
    const int cur = it & 1;
    if (it + 1 < NT) STAGE(kt + 1, cur ^ 1);

    const char* sKb = (const char*)&sK[cur][0];
    f32x16 sa0 = {}, sa1 = {};
    __builtin_amdgcn_s_setprio(1);
#pragma unroll
    for (int s = 0; s < 4; ++s) {
      f16x8 k0 = *(const f16x8*)(sKb + ((lq * 128 + s * 32 + hi * 16) ^ ((lq & 7) << 4)));
      f16x8 k1 = *(const f16x8*)(sKb + (((32 + lq) * 128 + s * 32 + hi * 16) ^ ((lq & 7) << 4)));
      sa0 = MFMA32(k0, qb[s], sa0);
      sa1 = MFMA32(k1, qb[s], sa1);
    }
    __builtin_amdgcn_s_setprio(0);

    float p_[32];
#pragma unroll
    for (int r = 0; r < 16; ++r) { p_[r] = sa0[r]; p_[16 + r] = sa1[r]; }

#pragma unroll
    for (int u = 0; u < 8; ++u) {
      int tt = u >> 2, j = u & 3;
      int kloc = it * 64 + tt * 32 + j * 8 + hi * 4;
      f16x4 pen4 = *(const f16x4*)&sPen[kloc];
      int bidx0 = w * 32 + lq - kloc + (KR - 1);
#pragma unroll
      for (int e = 0; e < 4; ++e) {
        float bp = sBias[bidx0 - e] + (float)pen4[e];
        int r = tt * 16 + j * 4 + e;
        p_[r] = p_[r] * c1 + bp;
      }
    }

    float mm[11];
#pragma unroll
    for (int r = 0; r < 10; ++r) mm[r] = fmax3(p_[3 * r], p_[3 * r + 1], p_[3 * r + 2]);
    mm[10] = fmaxf(p_[30], p_[31]);
    float a0 = fmax3(mm[0], mm[1], mm[2]);
    float a1 = fmax3(mm[3], mm[4], mm[5]);
    float a2 = fmax3(mm[6], mm[7], mm[8]);
    float a3 = fmax3(mm[9], mm[10], a0);
    float mx = fmax3(a1, a2, a3);
    mx = fmaxf(mx, __shfl_xor(mx, 32));

    if (__any(mx > m_r + 8.0f)) {
      float mnew = fmaxf(m_r, mx);
      float al = ex2(m_r - mnew);
      m_r = mnew;
#pragma unroll
      for (int r = 0; r < 16; ++r) { oacc0[r] *= al; oacc1[r] *= al; oaccL[r] *= al; }
    }

#pragma unroll
    for (int r = 0; r < 32; ++r) p_[r] = ex2(p_[r] - m_r);

    f16x8 pf[4];
#pragma unroll
    for (int sl = 0; sl < 4; ++sl) {
      int tt = sl >> 1, sp = sl & 1;
      int bA = tt * 16 + (2 * sp) * 4, bB = tt * 16 + (2 * sp + 1) * 4;
      u32 A0 = pkr(p_[bA], p_[bA + 1]);
      u32 A1 = pkr(p_[bA + 2], p_[bA + 3]);
      u32 B0 = pkr(p_[bB], p_[bB + 1]);
      u32 B1 = pkr(p_[bB + 2], p_[bB + 3]);
      asm volatile("v_permlane32_swap_b32 %0, %1" : "+v"(A0), "+v"(B0));
      asm volatile("v_permlane32_swap_b32 %0, %1" : "+v"(A1), "+v"(B1));
      union { u32 u[4]; f16x8 v; } c;
      c.u[0] = A0; c.u[1] = A1; c.u[2] = B0; c.u[3] = B1;
      pf[sl] = c.v;
    }

    const char* sVb = (const char*)&sVT[cur][0];
    __builtin_amdgcn_s_setprio(1);
#pragma unroll
    for (int sl = 0; sl < 4; ++sl) {
      int K0 = sl * 16;
      f16x8 v0 = *(const f16x8*)(sVb + ((lq * 128 + K0 * 2 + hi * 16) ^ ((lq & 7) << 4)));
      f16x8 v1 = *(const f16x8*)(sVb + (((32 + lq) * 128 + K0 * 2 + hi * 16) ^ ((lq & 7) << 4)));
      oacc0 = MFMA32(v0, pf[sl], oacc0);
      oacc1 = MFMA32(v1, pf[sl], oacc1);
      oaccL = MFMA32(ones, pf[sl], oaccL);
    }
    __builtin_amdgcn_s_setprio(0);
    __syncthreads();
  }

  const float l = oaccL[0];
  const float rinv = l > 0.0f ? 1.0f / l : 0.0f;
  if constexpr (SPLIT == 1) {
    const size_t orow = ((size_t)b * LQ + (q0w + lq)) * D_MODEL + h * DHEAD;
#pragma unroll
    for (int dh = 0; dh < 2; ++dh)
#pragma unroll
      for (int j = 0; j < 4; ++j) {
        int d0 = dh * 32 + j * 8 + hi * 4;
        f16x4 ov;
#pragma unroll
        for (int e = 0; e < 4; ++e)
          ov[e] = (f16)((dh ? oacc1[j * 4 + e] : oacc0[j * 4 + e]) * rinv);
        *(f16x4*)(OUT + orow + d0) = ov;
      }
  } else {
    const size_t row = (size_t)bh * 2048 + (q0w + lq);
    const size_t prow = ((size_t)half * 65536 + row) * 64;
#pragma unroll
    for (int dh = 0; dh < 2; ++dh)
#pragma unroll
      for (int j = 0; j < 4; ++j) {
        int d0 = dh * 32 + j * 8 + hi * 4;
        f16x4 ov;
#pragma unroll
        for (int e = 0; e < 4; ++e)
          ov[e] = (f16)((dh ? oacc1[j * 4 + e] : oacc0[j * 4 + e]) * rinv);
        *(f16x4*)(OUT + prow + d0) = ov;
      }
    if (hi == 0)
      ((float2*)ML)[half * 65536 + row] = make_float2(m_r, l);
  }
}

// combine two KV-split partials: O = w0*O0 + w1*O1, w_i = exp2(m_i - M)*l_i / sum
__global__ void k_combine(const f16* __restrict__ P16, const float* __restrict__ ML,
                          f16* __restrict__ O16) {
  const int idx = blockIdx.x * 256 + threadIdx.x;  // 524288
  const int row = idx >> 3;
  const int dg = (idx & 7) * 8;
  float2 ml0 = ((const float2*)ML)[row];
  float2 ml1 = ((const float2*)ML)[65536 + row];
  float M = fmaxf(ml0.x, ml1.x);
  float w0 = ex2(ml0.x - M) * ml0.y;
  float w1 = ex2(ml1.x - M) * ml1.y;
  float rd = 1.0f / (w0 + w1);
  w0 *= rd; w1 *= rd;
  f16x8 o0 = *(const f16x8*)(P16 + (size_t)row * 64 + dg);
  f16x8 o1 = *(const f16x8*)(P16 + ((size_t)65536 + row) * 64 + dg);
  const int bh = row >> 11, qq = row & 2047;
  const int b = bh >> 4, h = bh & 15;
  f16x8 ov;
#pragma unroll
  for (int e = 0; e < 8; ++e)
    ov[e] = (f16)(w0 * (float)o0[e] + w1 * (float)o1[e]);
  *(f16x8*)(O16 + ((size_t)b * LQ + qq) * D_MODEL + h * DHEAD + dg) = ov;
}

// ---------------- launch ----------------
// ws plan (57 MB):
//  slab0 Xq  -> P16 half0 (after qkv)     slab4 KHp
//  slab1 Xk  -> P16 half1                 slab5 VTp
//  slab2 Xv  -> ML                        slab6 W16
//  slab3 QHp -> O16 (after attn)          ws+7*SL: BIAS + M8
extern "C" void kernel_launch(void* const* d_in, const int* in_sizes, int n_in,
                              void* d_out, int out_size, void* d_ws, size_t ws_size,
                              hipStream_t stream) {
  (void)in_sizes; (void)n_in; (void)out_size; (void)ws_size;
  const float* q   = (const float*)d_in[0];
  const float* k   = (const float*)d_in[1];
  const float* v   = (const float*)d_in[2];
  const void*  msk = d_in[3];
  const float* Wq  = (const float*)d_in[4];
  const float* Wk  = (const float*)d_in[5];
  const float* Wv  = (const float*)d_in[6];
  const float* Wo  = (const float*)d_in[7];
  const float* rel = (const float*)d_in[8];

  char* ws = (char*)d_ws;
  const size_t SL = (size_t)8 << 20;
  f16* Xq  = (f16*)(ws + 0 * SL);
  f16* Xk  = (f16*)(ws + 1 * SL);
  f16* Xv  = (f16*)(ws + 2 * SL);
  f16* QHp = (f16*)(ws + 3 * SL);
  f16* KHp = (f16*)(ws + 4 * SL);
  f16* VTp = (f16*)(ws + 5 * SL);
  f16* W16 = (f16*)(ws + 6 * SL);
  f16* P16 = (f16*)(ws + 0 * SL);          // overlays Xq+Xk (dead after qkv)
  float* ML = (float*)(ws + 2 * SL);       // overlays Xv (dead after qkv)
  f16* O16 = (f16*)(ws + 3 * SL);          // overlays QHp (dead after attn)
  char* misc = ws + 7 * SL;
  float* BIAS = (float*)misc;
  unsigned char* M8 = (unsigned char*)(misc + (192 << 10));

  k_cvt_prep<<<16386, 256, 0, stream>>>(q, k, v, Wq, Wk, Wv, Wo, Xq, Xk, Xv, W16,
                                        msk, rel, BIAS, M8);
  k_gemm_qkv<<<dim3(32, 8, 3), 256, 0, stream>>>(Xq, Xk, Xv, W16, QHp, KHp, VTp);
  k_attn<2><<<1024, 256, 0, stream>>>(QHp, KHp, VTp, BIAS, M8, P16, ML);
  k_combine<<<2048, 256, 0, stream>>>(P16, ML, O16);
  k_gemm_o<<<dim3(32, 16), 256, 0, stream>>>(O16, W16 + 3 * 1048576, (float*)d_out);
}

// Round 11
// 149.459 us; speedup vs baseline: 1.5959x; 1.0893x over previous
//
#include <hip/hip_runtime.h>
#include <math.h>

typedef _Float16 f16;
typedef __fp16 h16x2 __attribute__((ext_vector_type(2)));
typedef _Float16 f16x4 __attribute__((ext_vector_type(4)));
typedef _Float16 f16x8 __attribute__((ext_vector_type(8)));
typedef float f32x4 __attribute__((ext_vector_type(4)));
typedef float f32x16 __attribute__((ext_vector_type(16)));
typedef unsigned int u32;

#define D_MODEL 1024
#define NHEADS 16
#define DHEAD 64
#define LQ 2048
#define LKK 2048
#define BB 2
#define LOG2E 1.4426950408889634f

static __device__ __forceinline__ void gload16(const void* g, void* l) {
  __builtin_amdgcn_global_load_lds(
      (const __attribute__((address_space(1))) u32*)g,
      (__attribute__((address_space(3))) u32*)l, 16, 0, 0);
}
static __device__ __forceinline__ float ex2(float x) {
  float r;
  asm volatile("v_exp_f32 %0, %1\n\ts_nop 0" : "=v"(r) : "v"(x));
  return r;
}
static __device__ __forceinline__ u32 pkr(float a, float b) {
  union { h16x2 h; u32 u; } c;
  c.h = __builtin_amdgcn_cvt_pkrtz(a, b);
  return c.u;
}
static __device__ __forceinline__ float fmax3(float a, float b, float c) {
  return fmaxf(fmaxf(a, b), c);
}
#define MFMA16(a, b, c) __builtin_amdgcn_mfma_f32_16x16x32_f16(a, b, c, 0, 0, 0)
#define MFMA32(a, b, c) __builtin_amdgcn_mfma_f32_32x32x16_f16(a, b, c, 0, 0, 0)

// ---------------- W convert + prep (mask detect/convert, bias table) ----------------
__global__ void k_cvtw_prep(const float* Wq, const float* Wk, const float* Wv, const float* Wo,
                            f16* W16, const void* msk, const float* __restrict__ rel,
                            float* __restrict__ biasT, unsigned char* __restrict__ m8) {
  const int blk = blockIdx.x;
  const int t = threadIdx.x;
  if (blk < 4096) {  // W fp32->fp16: 1M float4
    int i = blk * 256 + t;
    int which = i >> 18, off = i & 262143;
    const float* s = which == 0 ? Wq : (which == 1 ? Wk : (which == 2 ? Wv : Wo));
    float4 x = ((const float4*)s)[off];
    f16x4 o; o[0] = (f16)x.x; o[1] = (f16)x.y; o[2] = (f16)x.z; o[3] = (f16)x.w;
    ((f16x4*)(W16 + (size_t)which * 1048576))[off] = o;
    return;
  }
  if (blk == 4096) {  // mask dtype detect + convert to u8
    __shared__ int o1s, o2s;
    if (t == 0) { o1s = 0; o2s = 0; }
    __syncthreads();
    const unsigned char* raw = (const unsigned char*)msk;
    int o1 = 0, o2 = 0;
    for (int i = t; i < BB * LKK; i += 256) {
      unsigned char vv = raw[i];
      if ((i & 3) && vv) o1 = 1;
      if (((i & 3) == 2) && vv == 0x80u) o2 = 1;
    }
    if (o1) atomicOr(&o1s, 1);
    if (o2) atomicOr(&o2s, 1);
    __syncthreads();
    const int f = o1s ? (o2s ? 2 : 1) : 0;  // 0=int32, 1=bool, 2=f32
    for (int i = t; i < BB * LKK; i += 256) {
      unsigned char vv;
      if (f == 0)      vv = (((const int*)msk)[i] != 0);
      else if (f == 1) vv = (((const unsigned char*)msk)[i] != 0);
      else             vv = (((const float*)msk)[i] != 0.0f);
      m8[i] = vv;
    }
    return;
  }
  // blk == 4097: bias table, pre-scaled by log2e
  for (int n = t; n < 2048; n += 256) {
    int bucket;
    if (n < 16) bucket = n;
    else {
      float tt = logf((float)n / 16.0f + 1e-9f);  // exact jax op order
      tt = tt / 2.0794415416798357f;
      tt = tt * 16.0f;
      bucket = 16 + (int)tt;
      if (bucket > 31) bucket = 31;
    }
    for (int h = 0; h < NHEADS; ++h)
      biasT[h * 2048 + n] = rel[bucket * NHEADS + h] * LOG2E;
  }
}

// ---------------- GEMM core: C = A[4096,1024] * B[1024,1024]^T, tile 128 x BN ----------------
// Double-buffered LDS, ONE barrier per K-step. sA: 2 x 4096 f16 (8192 B/buf).
// AF32: A is fp32; LOADA(kk+1) issued BEFORE COMPUTE (latency hides under MFMAs),
// cvt+LDS-write after COMPUTE. Identical RTE numerics to a separate cvt pass.
// EPI 0: f16 scatter [B,H,L,64].  EPI 1: fp32 row-major.  EPI 2: f16 V^T [B,H,64,L].
template <int EPI, int BN, bool AF32>
static __device__ __forceinline__ void gemm_core(const void* __restrict__ Av,
                                                 const f16* __restrict__ Bm,
                                                 void* __restrict__ C,
                                                 f16* sA, f16* sB) {
  constexpr int JN = BN / 32;
  const int t = threadIdx.x;
  const int w = t >> 6, lane = t & 63;
  const int lg = lane >> 4, lc = lane & 15;
  const int wr = w >> 1, wc = w & 1;
  const long row0 = (long)blockIdx.x * 128;
  const long col0 = (long)blockIdx.y * BN;
  f32x4 acc[4][JN] = {};

  const int rA0 = t >> 2, kA0 = t & 3;
  const int rA1 = (t + 256) >> 2;

  float4 a[4];  // AF32 reg stage (2 chunks x 2 float4)

  auto LOADA = [&](int kk) {
    const float* s0 = (const float*)Av + (row0 + rA0) * 1024 + kk * 32 + kA0 * 8;
    const float* s1 = (const float*)Av + (row0 + rA1) * 1024 + kk * 32 + kA0 * 8;
    a[0] = *(const float4*)s0; a[1] = *(const float4*)(s0 + 4);
    a[2] = *(const float4*)s1; a[3] = *(const float4*)(s1 + 4);
  };
  auto WRITEA = [&](int buf) {
    f16x8 o0, o1;
    o0[0] = (f16)a[0].x; o0[1] = (f16)a[0].y; o0[2] = (f16)a[0].z; o0[3] = (f16)a[0].w;
    o0[4] = (f16)a[1].x; o0[5] = (f16)a[1].y; o0[6] = (f16)a[1].z; o0[7] = (f16)a[1].w;
    o1[0] = (f16)a[2].x; o1[1] = (f16)a[2].y; o1[2] = (f16)a[2].z; o1[3] = (f16)a[2].w;
    o1[4] = (f16)a[3].x; o1[5] = (f16)a[3].y; o1[6] = (f16)a[3].z; o1[7] = (f16)a[3].w;
    *(f16x8*)((char*)sA + buf * 8192 + t * 16) = o0;                // conflict-free b128
    *(f16x8*)((char*)sA + buf * 8192 + (t + 256) * 16) = o1;
  };
  auto STAGEA16 = [&](int kk, int buf) {
    gload16((const f16*)Av + (row0 + rA0) * 1024 + kk * 32 + kA0 * 8,
            (char*)sA + buf * 8192 + t * 16);
    gload16((const f16*)Av + (row0 + rA1) * 1024 + kk * 32 + kA0 * 8,
            (char*)sA + buf * 8192 + (t + 256) * 16);
  };
  auto STAGEB = [&](int kk, int buf) {
#pragma unroll
    for (int it = 0; it < BN / 64; ++it) {
      int ch = t + it * 256;
      int r = ch >> 2, kq = ch & 3;
      gload16(Bm + (col0 + r) * 1024 + kk * 32 + kq * 8, (char*)sB + buf * BN * 64 + ch * 16);
    }
  };
  auto COMPUTE = [&](int buf) {
    f16x8 af[4], bf[JN];
#pragma unroll
    for (int i = 0; i < 4; ++i)
      af[i] = *(const f16x8*)&sA[buf * 4096 + (wr * 64 + i * 16 + lc) * 32 + lg * 8];
#pragma unroll
    for (int j = 0; j < JN; ++j)
      bf[j] = *(const f16x8*)&sB[buf * BN * 32 + (wc * (16 * JN) + j * 16 + lc) * 32 + lg * 8];
#pragma unroll
    for (int i = 0; i < 4; ++i)
#pragma unroll
      for (int j = 0; j < JN; ++j)
        acc[i][j] = MFMA16(af[i], bf[j], acc[i][j]);
  };

  if constexpr (AF32) { LOADA(0); WRITEA(0); } else { STAGEA16(0, 0); }
  STAGEB(0, 0);
  __syncthreads();

  for (int kk = 0; kk < 32; ++kk) {
    const int cur = kk & 1;
    if (kk < 31) {
      if constexpr (AF32) { LOADA(kk + 1); } else { STAGEA16(kk + 1, cur ^ 1); }
      STAGEB(kk + 1, cur ^ 1);
    }
    COMPUTE(cur);
    if (kk < 31) { if constexpr (AF32) WRITEA(cur ^ 1); }
    __syncthreads();
  }

#pragma unroll
  for (int i = 0; i < 4; ++i)
#pragma unroll
    for (int j = 0; j < JN; ++j) {
      const long rowb = row0 + wr * 64 + i * 16 + lg * 4;
      const long col = col0 + wc * (16 * JN) + j * 16 + lc;
      if (EPI == 2) {  // V^T: [b,h,d,l] with f16x4 over l
        long b = rowb >> 11, l0 = rowb & 2047;
        long h = col >> 6, d = col & 63;
        f16x4 ov;
#pragma unroll
        for (int r = 0; r < 4; ++r) ov[r] = (f16)acc[i][j][r];
        *(f16x4*)((f16*)C + (((b * NHEADS + h) * DHEAD + d) * (long)LKK + l0)) = ov;
      } else {
#pragma unroll
        for (int r = 0; r < 4; ++r) {
          long row = rowb + r;
          float vv = acc[i][j][r];
          if (EPI == 0) {
            long b = row >> 11, l = row & 2047;
            long h = col >> 6, d = col & 63;
            ((f16*)C)[(((b * NHEADS + h) * LQ) + l) * DHEAD + d] = (f16)vv;
          } else {
            ((float*)C)[row * 1024 + col] = vv;
          }
        }
      }
    }
}

__global__ void __launch_bounds__(256, 3)
k_gemm_qkv(const float* __restrict__ q, const float* __restrict__ k, const float* __restrict__ v,
           const f16* __restrict__ W16, f16* __restrict__ QHp, f16* __restrict__ KHp,
           f16* __restrict__ VTp) {
  __shared__ __align__(16) f16 smem[16384];  // 32 KB shared by both branches
  f16* sA = smem;          // 2 bufs x 4096 f16
  f16* sB = smem + 8192;   // 2 bufs x 4096 f16
  const int z = blockIdx.z;
  if (z == 2) {
    gemm_core<2, 128, true>(v, W16 + 2 * 1048576, VTp, sA, sB);
  } else {
    const float* A = z == 0 ? q : k;
    f16* C = z == 0 ? QHp : KHp;
    gemm_core<0, 128, true>(A, W16 + (size_t)z * 1048576, C, sA, sB);
  }
}

__global__ void __launch_bounds__(256, 2)
k_gemm_o(const f16* __restrict__ A, const f16* __restrict__ Bm, float* __restrict__ C) {
  __shared__ __align__(16) f16 smem[2 * 4096 + 2 * 2048];  // 24 KB
  gemm_core<1, 64, false>(A, Bm, C, smem, smem + 8192);
}

// ---------------- flash attention: LDS-staged K/V, SPLIT=1 (proven fastest) ----------------
// 4 warps/block, 32 q-rows/warp. Grid 512 = 16 qchunks x 32 (b,h), XCD-clustered.
__global__ void __launch_bounds__(256, 4)
k_attn(const f16* __restrict__ QH, const f16* __restrict__ KH, const f16* __restrict__ VT,
       const float* __restrict__ BIASg, const unsigned char* __restrict__ M8,
       f16* __restrict__ OUT) {
  constexpr int KR = LKK;
  constexpr int NT = KR / 64;
  __shared__ __align__(16) f16 sK[2][64 * 64];
  __shared__ __align__(16) f16 sVT[2][64 * 64];
  __shared__ __align__(16) float sBias[KR + 128];  // window n in [q0-2047, q0+128)
  __shared__ __align__(16) f16 sPen[KR + 8];       // 0 or -60000 (log2 domain)

  const int L = blockIdx.x;
  const int bh = (L & 7) * 4 + ((L >> 3) & 3);     // same-bh blocks -> same XCD
  const int qc = (L >> 5) & 15;
  const int b = bh >> 4, h = bh & 15;
  const int t = threadIdx.x, w = t >> 6, lane = t & 63;
  const int lq = lane & 31, hi = lane >> 5;
  const int q0 = qc * 128;
  const int q0w = q0 + w * 32;
  const size_t base = (size_t)bh * LKK * DHEAD;

  for (int i = t; i < KR + 128; i += 256) {
    int n = i - (KR - 1) + q0;
    n = n < 0 ? 0 : (n > 2047 ? 2047 : n);
    sBias[i] = BIASg[h * 2048 + n];
  }
  for (int i = t; i < KR; i += 256)
    sPen[i] = M8[b * LKK + i] ? (f16)0.0f : (f16)-60000.0f;

  f16x8 qb[4];
  const f16* qrow = QH + base + (size_t)(q0w + lq) * DHEAD;
#pragma unroll
  for (int s = 0; s < 4; ++s)
    qb[s] = *(const f16x8*)(qrow + s * 16 + hi * 8);

  const int ch0 = t, ch1 = t + 256;
  const int r0 = ch0 >> 3, g0 = ((ch0 & 7) ^ (r0 & 7)) * 8;
  const int r1 = ch1 >> 3, g1 = ((ch1 & 7) ^ (r1 & 7)) * 8;
  const f16* Kb = KH + base;
  const f16* Vb = VT + base;

  auto STAGE = [&](int kt, int buf) {
    const int k0 = kt * 64;
    gload16(Kb + (size_t)(k0 + r0) * DHEAD + g0, (char*)&sK[buf][0] + ch0 * 16);
    gload16(Kb + (size_t)(k0 + r1) * DHEAD + g1, (char*)&sK[buf][0] + ch1 * 16);
    gload16(Vb + (size_t)r0 * LKK + k0 + g0, (char*)&sVT[buf][0] + ch0 * 16);
    gload16(Vb + (size_t)r1 * LKK + k0 + g1, (char*)&sVT[buf][0] + ch1 * 16);
  };

  float m_r = -1e30f;
  f32x16 oacc0 = {}, oacc1 = {}, oaccL = {};
  const float c1 = 0.125f * LOG2E;
  f16x8 ones;
#pragma unroll
  for (int e = 0; e < 8; ++e) ones[e] = (f16)1.0f;

  STAGE(0, 0);
  __syncthreads();

  for (int it = 0; it < NT; ++it) {
    const int cur = it & 1;
    if (it + 1 < NT) STAGE(it + 1, cur ^ 1);

    const char* sKb = (const char*)&sK[cur][0];
    f32x16 sa0 = {}, sa1 = {};
    __builtin_amdgcn_s_setprio(1);
#pragma unroll
    for (int s = 0; s < 4; ++s) {
      f16x8 k0 = *(const f16x8*)(sKb + ((lq * 128 + s * 32 + hi * 16) ^ ((lq & 7) << 4)));
      f16x8 k1 = *(const f16x8*)(sKb + (((32 + lq) * 128 + s * 32 + hi * 16) ^ ((lq & 7) << 4)));
      sa0 = MFMA32(k0, qb[s], sa0);
      sa1 = MFMA32(k1, qb[s], sa1);
    }
    __builtin_amdgcn_s_setprio(0);

    float p_[32];
#pragma unroll
    for (int r = 0; r < 16; ++r) { p_[r] = sa0[r]; p_[16 + r] = sa1[r]; }

#pragma unroll
    for (int u = 0; u < 8; ++u) {
      int tt = u >> 2, j = u & 3;
      int kloc = it * 64 + tt * 32 + j * 8 + hi * 4;
      f16x4 pen4 = *(const f16x4*)&sPen[kloc];
      int bidx0 = w * 32 + lq - kloc + (KR - 1);
#pragma unroll
      for (int e = 0; e < 4; ++e) {
        float bp = sBias[bidx0 - e] + (float)pen4[e];
        int r = tt * 16 + j * 4 + e;
        p_[r] = p_[r] * c1 + bp;
      }
    }

    float mm[11];
#pragma unroll
    for (int r = 0; r < 10; ++r) mm[r] = fmax3(p_[3 * r], p_[3 * r + 1], p_[3 * r + 2]);
    mm[10] = fmaxf(p_[30], p_[31]);
    float a0 = fmax3(mm[0], mm[1], mm[2]);
    float a1 = fmax3(mm[3], mm[4], mm[5]);
    float a2 = fmax3(mm[6], mm[7], mm[8]);
    float a3 = fmax3(mm[9], mm[10], a0);
    float mx = fmax3(a1, a2, a3);
    mx = fmaxf(mx, __shfl_xor(mx, 32));

    if (__any(mx > m_r + 8.0f)) {
      float mnew = fmaxf(m_r, mx);
      float al = ex2(m_r - mnew);
      m_r = mnew;
#pragma unroll
      for (int r = 0; r < 16; ++r) { oacc0[r] *= al; oacc1[r] *= al; oaccL[r] *= al; }
    }

#pragma unroll
    for (int r = 0; r < 32; ++r) p_[r] = ex2(p_[r] - m_r);

    f16x8 pf[4];
#pragma unroll
    for (int sl = 0; sl < 4; ++sl) {
      int tt = sl >> 1, sp = sl & 1;
      int bA = tt * 16 + (2 * sp) * 4, bB = tt * 16 + (2 * sp + 1) * 4;
      u32 A0 = pkr(p_[bA], p_[bA + 1]);
      u32 A1 = pkr(p_[bA + 2], p_[bA + 3]);
      u32 B0 = pkr(p_[bB], p_[bB + 1]);
      u32 B1 = pkr(p_[bB + 2], p_[bB + 3]);
      asm volatile("v_permlane32_swap_b32 %0, %1" : "+v"(A0), "+v"(B0));
      asm volatile("v_permlane32_swap_b32 %0, %1" : "+v"(A1), "+v"(B1));
      union { u32 u[4]; f16x8 v; } c;
      c.u[0] = A0; c.u[1] = A1; c.u[2] = B0; c.u[3] = B1;
      pf[sl] = c.v;
    }

    const char* sVb = (const char*)&sVT[cur][0];
    __builtin_amdgcn_s_setprio(1);
#pragma unroll
    for (int sl = 0; sl < 4; ++sl) {
      int K0 = sl * 16;
      f16x8 v0 = *(const f16x8*)(sVb + ((lq * 128 + K0 * 2 + hi * 16) ^ ((lq & 7) << 4)));
      f16x8 v1 = *(const f16x8*)(sVb + (((32 + lq) * 128 + K0 * 2 + hi * 16) ^ ((lq & 7) << 4)));
      oacc0 = MFMA32(v0, pf[sl], oacc0);
      oacc1 = MFMA32(v1, pf[sl], oacc1);
      oaccL = MFMA32(ones, pf[sl], oaccL);
    }
    __builtin_amdgcn_s_setprio(0);
    __syncthreads();
  }

  const float l = oaccL[0];
  const float rinv = l > 0.0f ? 1.0f / l : 0.0f;
  const size_t orow = ((size_t)b * LQ + (q0w + lq)) * D_MODEL + h * DHEAD;
#pragma unroll
  for (int dh = 0; dh < 2; ++dh)
#pragma unroll
    for (int j = 0; j < 4; ++j) {
      int d0 = dh * 32 + j * 8 + hi * 4;
      f16x4 ov;
#pragma unroll
      for (int e = 0; e < 4; ++e)
        ov[e] = (f16)((dh ? oacc1[j * 4 + e] : oacc0[j * 4 + e]) * rinv);
      *(f16x4*)(OUT + orow + d0) = ov;
    }
}

// ---------------- launch ----------------
// ws plan (41 MB): slab0 QHp, slab1 KHp, slab2 VTp, slab3 O16, slab4 W16, slab5 misc.
extern "C" void kernel_launch(void* const* d_in, const int* in_sizes, int n_in,
                              void* d_out, int out_size, void* d_ws, size_t ws_size,
                              hipStream_t stream) {
  (void)in_sizes; (void)n_in; (void)out_size; (void)ws_size;
  const float* q   = (const float*)d_in[0];
  const float* k   = (const float*)d_in[1];
  const float* v   = (const float*)d_in[2];
  const void*  msk = d_in[3];
  const float* Wq  = (const float*)d_in[4];
  const float* Wk  = (const float*)d_in[5];
  const float* Wv  = (const float*)d_in[6];
  const float* Wo  = (const float*)d_in[7];
  const float* rel = (const float*)d_in[8];

  char* ws = (char*)d_ws;
  const size_t SL = (size_t)8 << 20;
  f16* QHp = (f16*)(ws + 0 * SL);
  f16* KHp = (f16*)(ws + 1 * SL);
  f16* VTp = (f16*)(ws + 2 * SL);
  f16* O16 = (f16*)(ws + 3 * SL);
  f16* W16 = (f16*)(ws + 4 * SL);
  char* misc = ws + 5 * SL;
  float* BIAS = (float*)misc;
  unsigned char* M8 = (unsigned char*)(misc + (192 << 10));

  k_cvtw_prep<<<4098, 256, 0, stream>>>(Wq, Wk, Wv, Wo, W16, msk, rel, BIAS, M8);
  k_gemm_qkv<<<dim3(32, 8, 3), 256, 0, stream>>>(q, k, v, W16, QHp, KHp, VTp);
  k_attn<<<512, 256, 0, stream>>>(QHp, KHp, VTp, BIAS, M8, O16);
  k_gemm_o<<<dim3(32, 16), 256, 0, stream>>>(O16, W16 + 3 * 1048576, (float*)d_out);
}

// Round 12
// 142.281 us; speedup vs baseline: 1.6765x; 1.0504x over previous
//
#include <hip/hip_runtime.h>
#include <math.h>

typedef _Float16 f16;
typedef __fp16 h16x2 __attribute__((ext_vector_type(2)));
typedef _Float16 f16x4 __attribute__((ext_vector_type(4)));
typedef _Float16 f16x8 __attribute__((ext_vector_type(8)));
typedef float f32x4 __attribute__((ext_vector_type(4)));
typedef float f32x16 __attribute__((ext_vector_type(16)));
typedef unsigned int u32;

#define D_MODEL 1024
#define NHEADS 16
#define DHEAD 64
#define LQ 2048
#define LKK 2048
#define BB 2
#define LOG2E 1.4426950408889634f

static __device__ __forceinline__ void gload16(const void* g, void* l) {
  __builtin_amdgcn_global_load_lds(
      (const __attribute__((address_space(1))) u32*)g,
      (__attribute__((address_space(3))) u32*)l, 16, 0, 0);
}
static __device__ __forceinline__ float ex2(float x) {
  float r;
  asm volatile("v_exp_f32 %0, %1\n\ts_nop 0" : "=v"(r) : "v"(x));
  return r;
}
static __device__ __forceinline__ u32 pkr(float a, float b) {
  union { h16x2 h; u32 u; } c;
  c.h = __builtin_amdgcn_cvt_pkrtz(a, b);
  return c.u;
}
static __device__ __forceinline__ float fmax3(float a, float b, float c) {
  return fmaxf(fmaxf(a, b), c);  // clang fuses to v_max3_f32
}
#define MFMA16(a, b, c) __builtin_amdgcn_mfma_f32_16x16x32_f16(a, b, c, 0, 0, 0)
#define MFMA32(a, b, c) __builtin_amdgcn_mfma_f32_32x32x16_f16(a, b, c, 0, 0, 0)

// ---------------- W convert + prep (mask detect/convert, bias table) ----------------
__global__ void k_cvtw_prep(const float* Wq, const float* Wk, const float* Wv, const float* Wo,
                            f16* W16, const void* msk, const float* __restrict__ rel,
                            float* __restrict__ biasT, unsigned char* __restrict__ m8) {
  const int blk = blockIdx.x;
  const int t = threadIdx.x;
  if (blk < 4096) {  // W fp32->fp16: 1M float4
    int i = blk * 256 + t;
    int which = i >> 18, off = i & 262143;
    const float* s = which == 0 ? Wq : (which == 1 ? Wk : (which == 2 ? Wv : Wo));
    float4 x = ((const float4*)s)[off];
    f16x4 o; o[0] = (f16)x.x; o[1] = (f16)x.y; o[2] = (f16)x.z; o[3] = (f16)x.w;
    ((f16x4*)(W16 + (size_t)which * 1048576))[off] = o;
    return;
  }
  if (blk == 4096) {  // mask dtype detect + convert to u8
    __shared__ int o1s, o2s;
    if (t == 0) { o1s = 0; o2s = 0; }
    __syncthreads();
    const unsigned char* raw = (const unsigned char*)msk;
    int o1 = 0, o2 = 0;
    for (int i = t; i < BB * LKK; i += 256) {
      unsigned char vv = raw[i];
      if ((i & 3) && vv) o1 = 1;
      if (((i & 3) == 2) && vv == 0x80u) o2 = 1;
    }
    if (o1) atomicOr(&o1s, 1);
    if (o2) atomicOr(&o2s, 1);
    __syncthreads();
    const int f = o1s ? (o2s ? 2 : 1) : 0;  // 0=int32, 1=bool, 2=f32
    for (int i = t; i < BB * LKK; i += 256) {
      unsigned char vv;
      if (f == 0)      vv = (((const int*)msk)[i] != 0);
      else if (f == 1) vv = (((const unsigned char*)msk)[i] != 0);
      else             vv = (((const float*)msk)[i] != 0.0f);
      m8[i] = vv;
    }
    return;
  }
  // blk == 4097: bias table, pre-scaled by log2e
  for (int n = t; n < 2048; n += 256) {
    int bucket;
    if (n < 16) bucket = n;
    else {
      float tt = logf((float)n / 16.0f + 1e-9f);  // exact jax op order
      tt = tt / 2.0794415416798357f;
      tt = tt * 16.0f;
      bucket = 16 + (int)tt;
      if (bucket > 31) bucket = 31;
    }
    for (int h = 0; h < NHEADS; ++h)
      biasT[h * 2048 + n] = rel[bucket * NHEADS + h] * LOG2E;
  }
}

// ---------------- GEMM core: C = A[4096,1024] * B[1024,1024]^T, tile 128 x BN ----------------
// Double-buffered LDS, ONE barrier per K-step. sA: 2 x 4096 f16 (8192 B/buf).
// AF32: A is fp32; LOADA(kk+1) issued BEFORE COMPUTE (latency hides under MFMAs),
// cvt+LDS-write after COMPUTE. Identical RTE numerics to a separate cvt pass.
// EPI 0: f16 scatter [B,H,L,64].  EPI 1: fp32 row-major.  EPI 2: f16 V^T [B,H,64,L].
template <int EPI, int BN, bool AF32>
static __device__ __forceinline__ void gemm_core(const void* __restrict__ Av,
                                                 const f16* __restrict__ Bm,
                                                 void* __restrict__ C,
                                                 f16* sA, f16* sB) {
  constexpr int JN = BN / 32;
  const int t = threadIdx.x;
  const int w = t >> 6, lane = t & 63;
  const int lg = lane >> 4, lc = lane & 15;
  const int wr = w >> 1, wc = w & 1;
  const long row0 = (long)blockIdx.x * 128;
  const long col0 = (long)blockIdx.y * BN;
  f32x4 acc[4][JN] = {};

  const int rA0 = t >> 2, kA0 = t & 3;
  const int rA1 = (t + 256) >> 2;

  float4 a[4];  // AF32 reg stage (2 chunks x 2 float4)

  auto LOADA = [&](int kk) {
    const float* s0 = (const float*)Av + (row0 + rA0) * 1024 + kk * 32 + kA0 * 8;
    const float* s1 = (const float*)Av + (row0 + rA1) * 1024 + kk * 32 + kA0 * 8;
    a[0] = *(const float4*)s0; a[1] = *(const float4*)(s0 + 4);
    a[2] = *(const float4*)s1; a[3] = *(const float4*)(s1 + 4);
  };
  auto WRITEA = [&](int buf) {
    f16x8 o0, o1;
    o0[0] = (f16)a[0].x; o0[1] = (f16)a[0].y; o0[2] = (f16)a[0].z; o0[3] = (f16)a[0].w;
    o0[4] = (f16)a[1].x; o0[5] = (f16)a[1].y; o0[6] = (f16)a[1].z; o0[7] = (f16)a[1].w;
    o1[0] = (f16)a[2].x; o1[1] = (f16)a[2].y; o1[2] = (f16)a[2].z; o1[3] = (f16)a[2].w;
    o1[4] = (f16)a[3].x; o1[5] = (f16)a[3].y; o1[6] = (f16)a[3].z; o1[7] = (f16)a[3].w;
    *(f16x8*)((char*)sA + buf * 8192 + t * 16) = o0;                // conflict-free b128
    *(f16x8*)((char*)sA + buf * 8192 + (t + 256) * 16) = o1;
  };
  auto STAGEA16 = [&](int kk, int buf) {
    gload16((const f16*)Av + (row0 + rA0) * 1024 + kk * 32 + kA0 * 8,
            (char*)sA + buf * 8192 + t * 16);
    gload16((const f16*)Av + (row0 + rA1) * 1024 + kk * 32 + kA0 * 8,
            (char*)sA + buf * 8192 + (t + 256) * 16);
  };
  auto STAGEB = [&](int kk, int buf) {
#pragma unroll
    for (int it = 0; it < BN / 64; ++it) {
      int ch = t + it * 256;
      int r = ch >> 2, kq = ch & 3;
      gload16(Bm + (col0 + r) * 1024 + kk * 32 + kq * 8, (char*)sB + buf * BN * 64 + ch * 16);
    }
  };
  auto COMPUTE = [&](int buf) {
    f16x8 af[4], bf[JN];
#pragma unroll
    for (int i = 0; i < 4; ++i)
      af[i] = *(const f16x8*)&sA[buf * 4096 + (wr * 64 + i * 16 + lc) * 32 + lg * 8];
#pragma unroll
    for (int j = 0; j < JN; ++j)
      bf[j] = *(const f16x8*)&sB[buf * BN * 32 + (wc * (16 * JN) + j * 16 + lc) * 32 + lg * 8];
#pragma unroll
    for (int i = 0; i < 4; ++i)
#pragma unroll
      for (int j = 0; j < JN; ++j)
        acc[i][j] = MFMA16(af[i], bf[j], acc[i][j]);
  };

  if constexpr (AF32) { LOADA(0); WRITEA(0); } else { STAGEA16(0, 0); }
  STAGEB(0, 0);
  __syncthreads();

  for (int kk = 0; kk < 32; ++kk) {
    const int cur = kk & 1;
    if (kk < 31) {
      if constexpr (AF32) { LOADA(kk + 1); } else { STAGEA16(kk + 1, cur ^ 1); }
      STAGEB(kk + 1, cur ^ 1);
    }
    COMPUTE(cur);
    if (kk < 31) { if constexpr (AF32) WRITEA(cur ^ 1); }
    __syncthreads();
  }

#pragma unroll
  for (int i = 0; i < 4; ++i)
#pragma unroll
    for (int j = 0; j < JN; ++j) {
      const long rowb = row0 + wr * 64 + i * 16 + lg * 4;
      const long col = col0 + wc * (16 * JN) + j * 16 + lc;
      if (EPI == 2) {  // V^T: [b,h,d,l] with f16x4 over l
        long b = rowb >> 11, l0 = rowb & 2047;
        long h = col >> 6, d = col & 63;
        f16x4 ov;
#pragma unroll
        for (int r = 0; r < 4; ++r) ov[r] = (f16)acc[i][j][r];
        *(f16x4*)((f16*)C + (((b * NHEADS + h) * DHEAD + d) * (long)LKK + l0)) = ov;
      } else {
#pragma unroll
        for (int r = 0; r < 4; ++r) {
          long row = rowb + r;
          float vv = acc[i][j][r];
          if (EPI == 0) {
            long b = row >> 11, l = row & 2047;
            long h = col >> 6, d = col & 63;
            ((f16*)C)[(((b * NHEADS + h) * LQ) + l) * DHEAD + d] = (f16)vv;
          } else {
            ((float*)C)[row * 1024 + col] = vv;
          }
        }
      }
    }
}

__global__ void __launch_bounds__(256, 3)
k_gemm_qkv(const float* __restrict__ q, const float* __restrict__ k, const float* __restrict__ v,
           const f16* __restrict__ W16, f16* __restrict__ QHp, f16* __restrict__ KHp,
           f16* __restrict__ VTp) {
  __shared__ __align__(16) f16 smem[16384];  // 32 KB shared by both branches
  f16* sA = smem;          // 2 bufs x 4096 f16
  f16* sB = smem + 8192;   // 2 bufs x 4096 f16
  const int z = blockIdx.z;
  if (z == 2) {
    gemm_core<2, 128, true>(v, W16 + 2 * 1048576, VTp, sA, sB);
  } else {
    const float* A = z == 0 ? q : k;
    f16* C = z == 0 ? QHp : KHp;
    gemm_core<0, 128, true>(A, W16 + (size_t)z * 1048576, C, sA, sB);
  }
}

__global__ void __launch_bounds__(256, 2)
k_gemm_o(const f16* __restrict__ A, const f16* __restrict__ Bm, float* __restrict__ C) {
  __shared__ __align__(16) f16 smem[2 * 4096 + 2 * 2048];  // 24 KB
  gemm_core<1, 64, false>(A, Bm, C, smem, smem + 8192);
}

// ---------------- flash attention (R4-proven 68.3µs version, restored verbatim) ----------------
// 4 warps/block, 32 q-rows/warp. Grid 512 = 16 qchunks x 32 (b,h), XCD-clustered.
__global__ void __launch_bounds__(256, 2)
k_attn(const f16* __restrict__ QH, const f16* __restrict__ KH, const f16* __restrict__ VT,
       const float* __restrict__ BIASg, const unsigned char* __restrict__ M8,
       f16* __restrict__ O16) {
  __shared__ __align__(16) f16 sK[2][64 * 64];   // K tiles, XOR-swizzled rows
  __shared__ __align__(16) f16 sVT[2][64 * 64];  // V^T tiles, XOR-swizzled rows
  __shared__ __align__(16) float sBias[4104];    // bias*log2e, padded for n<0
  __shared__ __align__(16) float sPen[2048];     // mask penalty (log2 domain)

  const int L = blockIdx.x;
  const int bh = (L & 7) * 4 + ((L >> 3) & 3);   // same-bh blocks -> same XCD
  const int qc = L >> 5;
  const int b = bh >> 4, h = bh & 15;
  const int t = threadIdx.x, w = t >> 6, lane = t & 63;
  const int lq = lane & 31, hi = lane >> 5;
  const int q0w = qc * 128 + w * 32;
  const size_t base = (size_t)bh * LKK * DHEAD;

  for (int i = t; i < 4104; i += 256) {
    int n = i - 2052; n = n < 0 ? 0 : (n > 2047 ? 2047 : n);
    sBias[i] = BIASg[h * 2048 + n];
  }
  for (int i = t; i < 2048; i += 256)
    sPen[i] = M8[b * LKK + i] ? 0.0f : -3.0e9f;

  f16x8 qb[4];
  const f16* qrow = QH + base + (size_t)(q0w + lq) * DHEAD;
#pragma unroll
  for (int s = 0; s < 4; ++s)
    qb[s] = *(const f16x8*)(qrow + s * 16 + hi * 8);

  const int ch0 = t, ch1 = t + 256;
  const int r0 = ch0 >> 3, g0 = ((ch0 & 7) ^ (r0 & 7)) * 8;
  const int r1 = ch1 >> 3, g1 = ((ch1 & 7) ^ (r1 & 7)) * 8;
  const f16* Kb = KH + base;
  const f16* Vb = VT + base;

  auto STAGE = [&](int kt, int buf) {
    const int k0 = kt * 64;
    gload16(Kb + (size_t)(k0 + r0) * DHEAD + g0, (char*)&sK[buf][0] + ch0 * 16);
    gload16(Kb + (size_t)(k0 + r1) * DHEAD + g1, (char*)&sK[buf][0] + ch1 * 16);
    gload16(Vb + (size_t)r0 * LKK + k0 + g0, (char*)&sVT[buf][0] + ch0 * 16);
    gload16(Vb + (size_t)r1 * LKK + k0 + g1, (char*)&sVT[buf][0] + ch1 * 16);
  };

  float m_r = -1e30f;
  f32x16 oacc0 = {}, oacc1 = {}, oaccL = {};
  const float c1 = 0.125f * LOG2E;
  f16x8 ones;
#pragma unroll
  for (int e = 0; e < 8; ++e) ones[e] = (f16)1.0f;

  STAGE(0, 0);
  __syncthreads();

  for (int kt = 0; kt < 32; ++kt) {
    const int cur = kt & 1;
    if (kt < 31) STAGE(kt + 1, cur ^ 1);

    // S^T = K * Q^T : lane owns q-col lq; rows = k
    const char* sKb = (const char*)&sK[cur][0];
    f32x16 sa0 = {}, sa1 = {};
#pragma unroll
    for (int s = 0; s < 4; ++s) {
      f16x8 k0 = *(const f16x8*)(sKb + ((lq * 128 + s * 32 + hi * 16) ^ ((lq & 7) << 4)));
      f16x8 k1 = *(const f16x8*)(sKb + (((32 + lq) * 128 + s * 32 + hi * 16) ^ ((lq & 7) << 4)));
      sa0 = MFMA32(k0, qb[s], sa0);
      sa1 = MFMA32(k1, qb[s], sa1);
    }

    float p_[32];
#pragma unroll
    for (int r = 0; r < 16; ++r) { p_[r] = sa0[r]; p_[16 + r] = sa1[r]; }

    // scale + bias + mask penalty (log2 domain): k = kt*64 + tt*32 + j*8 + hi*4 + e
#pragma unroll
    for (int u = 0; u < 8; ++u) {
      int tt = u >> 2, j = u & 3;
      int kbase = kt * 64 + tt * 32 + j * 8 + hi * 4;
      f32x4 pen4 = *(const f32x4*)&sPen[kbase];
      int bidx0 = (q0w + lq) - kbase + 2052;
#pragma unroll
      for (int e = 0; e < 4; ++e) {
        float bp = sBias[bidx0 - e] + pen4[e];
        int r = tt * 16 + j * 4 + e;
        p_[r] = p_[r] * c1 + bp;
      }
    }

    // row max: max3 triples + cross-half exchange
    float mm[11];
#pragma unroll
    for (int r = 0; r < 10; ++r) mm[r] = fmax3(p_[3 * r], p_[3 * r + 1], p_[3 * r + 2]);
    mm[10] = fmaxf(p_[30], p_[31]);
    float a0 = fmax3(mm[0], mm[1], mm[2]);
    float a1 = fmax3(mm[3], mm[4], mm[5]);
    float a2 = fmax3(mm[6], mm[7], mm[8]);
    float a3 = fmax3(mm[9], mm[10], a0);
    float mx = fmax3(a1, a2, a3);
    mx = fmaxf(mx, __shfl_xor(mx, 32));

    // defer-max rescale (THR=8 in log2 domain)
    if (__any(mx > m_r + 8.0f)) {
      float mnew = fmaxf(m_r, mx);
      float al = ex2(m_r - mnew);
      m_r = mnew;
#pragma unroll
      for (int r = 0; r < 16; ++r) { oacc0[r] *= al; oacc1[r] *= al; oaccL[r] *= al; }
    }

#pragma unroll
    for (int r = 0; r < 32; ++r) p_[r] = ex2(p_[r] - m_r);

    // pack P -> f16 B-frags via cvt_pk + permlane32_swap (T12)
    f16x8 pf[4];
#pragma unroll
    for (int sl = 0; sl < 4; ++sl) {
      int tt = sl >> 1, sp = sl & 1;
      int bA = tt * 16 + (2 * sp) * 4, bB = tt * 16 + (2 * sp + 1) * 4;
      u32 A0 = pkr(p_[bA], p_[bA + 1]);
      u32 A1 = pkr(p_[bA + 2], p_[bA + 3]);
      u32 B0 = pkr(p_[bB], p_[bB + 1]);
      u32 B1 = pkr(p_[bB + 2], p_[bB + 3]);
      asm volatile("v_permlane32_swap_b32 %0, %1" : "+v"(A0), "+v"(B0));
      asm volatile("v_permlane32_swap_b32 %0, %1" : "+v"(A1), "+v"(B1));
      union { u32 u[4]; f16x8 v; } c;
      c.u[0] = A0; c.u[1] = A1; c.u[2] = B0; c.u[3] = B1;
      pf[sl] = c.v;
    }

    // O^T += V^T * P (rows = d); l-row via ones-MFMA on the matrix pipe
    const char* sVb = (const char*)&sVT[cur][0];
#pragma unroll
    for (int sl = 0; sl < 4; ++sl) {
      int K0 = sl * 16;
      f16x8 v0 = *(const f16x8*)(sVb + ((lq * 128 + K0 * 2 + hi * 16) ^ ((lq & 7) << 4)));
      f16x8 v1 = *(const f16x8*)(sVb + (((32 + lq) * 128 + K0 * 2 + hi * 16) ^ ((lq & 7) << 4)));
      oacc0 = MFMA32(v0, pf[sl], oacc0);
      oacc1 = MFMA32(v1, pf[sl], oacc1);
      oaccL = MFMA32(ones, pf[sl], oaccL);
    }
    __syncthreads();
  }

  // normalize + store (lane owns q-row); l = any row of oaccL
  const float rinv = 1.0f / oaccL[0];
  const size_t orow = ((size_t)b * LQ + (q0w + lq)) * D_MODEL + h * DHEAD;
#pragma unroll
  for (int dh = 0; dh < 2; ++dh)
#pragma unroll
    for (int j = 0; j < 4; ++j) {
      int d0 = dh * 32 + j * 8 + hi * 4;
      f16x4 ov;
#pragma unroll
      for (int e = 0; e < 4; ++e) {
        float x = (dh ? oacc1[j * 4 + e] : oacc0[j * 4 + e]) * rinv;
        ov[e] = (f16)x;
      }
      *(f16x4*)(O16 + orow + d0) = ov;
    }
}

// ---------------- launch ----------------
// ws plan (41 MB): slab0 QHp, slab1 KHp, slab2 VTp, slab3 O16, slab4 W16, slab5 misc.
extern "C" void kernel_launch(void* const* d_in, const int* in_sizes, int n_in,
                              void* d_out, int out_size, void* d_ws, size_t ws_size,
                              hipStream_t stream) {
  (void)in_sizes; (void)n_in; (void)out_size; (void)ws_size;
  const float* q   = (const float*)d_in[0];
  const float* k   = (const float*)d_in[1];
  const float* v   = (const float*)d_in[2];
  const void*  msk = d_in[3];
  const float* Wq  = (const float*)d_in[4];
  const float* Wk  = (const float*)d_in[5];
  const float* Wv  = (const float*)d_in[6];
  const float* Wo  = (const float*)d_in[7];
  const float* rel = (const float*)d_in[8];

  char* ws = (char*)d_ws;
  const size_t SL = (size_t)8 << 20;
  f16* QHp = (f16*)(ws + 0 * SL);
  f16* KHp = (f16*)(ws + 1 * SL);
  f16* VTp = (f16*)(ws + 2 * SL);
  f16* O16 = (f16*)(ws + 3 * SL);
  f16* W16 = (f16*)(ws + 4 * SL);
  char* misc = ws + 5 * SL;
  float* BIAS = (float*)misc;
  unsigned char* M8 = (unsigned char*)(misc + (192 << 10));

  k_cvtw_prep<<<4098, 256, 0, stream>>>(Wq, Wk, Wv, Wo, W16, msk, rel, BIAS, M8);
  k_gemm_qkv<<<dim3(32, 8, 3), 256, 0, stream>>>(q, k, v, W16, QHp, KHp, VTp);
  k_attn<<<512, 256, 0, stream>>>(QHp, KHp, VTp, BIAS, M8, O16);
  k_gemm_o<<<dim3(32, 16), 256, 0, stream>>>(O16, W16 + 3 * 1048576, (float*)d_out);
}